// Round 3
// baseline (2108.472 us; speedup 1.0000x reference)
//
#include <hip/hip_runtime.h>
#include <hip/hip_bf16.h>
#include <stdint.h>

typedef unsigned short u16;
typedef unsigned int u32;
typedef short short8 __attribute__((ext_vector_type(8)));
typedef float f32x4 __attribute__((ext_vector_type(4)));

// Verified m201 sync idiom: builtin barrier (no implicit waitcnt drain),
// clobber-free waitcnt asm. A "memory" clobber here makes the backend emit
// s_waitcnt vmcnt(0) lgkmcnt(0) before the asm -> kills the pipeline.
#define SBAR()   __builtin_amdgcn_s_barrier()
#define WAITV(n) asm volatile("s_waitcnt vmcnt(" #n ")")
#define WAITL0() asm volatile("s_waitcnt lgkmcnt(0)")

__device__ __forceinline__ float bl(u32 x){ return __uint_as_float(x<<16); }
__device__ __forceinline__ float bh(u32 x){ return __uint_as_float(x & 0xffff0000u); }
__device__ __forceinline__ float b2f(u16 x){ return __uint_as_float(((u32)x)<<16); }
__device__ __forceinline__ u16 f2b(float f){
  u32 u = __float_as_uint(f);
  u32 r = (u + 0x7fffu + ((u>>16)&1u)) >> 16;
  return (u16)r;
}
__device__ __forceinline__ u32 pk2(float a, float b){ return (u32)f2b(a) | ((u32)f2b(b)<<16); }
__device__ __forceinline__ float tanh_f(float x){ return 1.f - 2.f/(__expf(2.f*x)+1.f); }
__device__ __forceinline__ float sigm(float x){ return 1.f/(1.f+__expf(-x)); }
__device__ __forceinline__ float gelu_t(float x){
  float u = 0.7978845608028654f*(x + 0.044715f*x*x*x);
  return 0.5f*x*(1.f + tanh_f(u));
}
// async global->LDS, 16B per lane; lds base must be wave-uniform
__device__ __forceinline__ void gld_lds16(const u16* g, u16* lds_base){
  __builtin_amdgcn_global_load_lds((const __attribute__((address_space(1))) void*)g,
                                   (__attribute__((address_space(3))) void*)lds_base,
                                   16, 0, 0);
}

// ---------------- transpose f32 [R,C] -> bf16 [C,R] ----------------
__global__ void transpose_f2b(const float* __restrict__ in, u16* __restrict__ out, int R, int C){
  __shared__ u16 t[32][33];
  int c0 = blockIdx.x*32, r0 = blockIdx.y*32;
  int tx = threadIdx.x, ty = threadIdx.y;   // 32 x 8
  #pragma unroll
  for (int i=0;i<4;++i) t[ty+i*8][tx] = f2b(in[(size_t)(r0+ty+i*8)*C + c0+tx]);
  __syncthreads();
  #pragma unroll
  for (int i=0;i<4;++i) out[(size_t)(c0+ty+i*8)*R + r0+tx] = t[tx][ty+i*8];
}

// ---------------- silu ----------------
__global__ void silu_k(const float* __restrict__ c, float* __restrict__ cs){
  int i = blockIdx.x*256 + threadIdx.x;
  float v = c[i];
  cs[i] = v * sigm(v);
}

// ---------------- b_ih + b_hh ----------------
__global__ void add_bias(const float* __restrict__ a, const float* __restrict__ b,
                         float* __restrict__ o){
  int i = blockIdx.x*256 + threadIdx.x;
  o[i] = a[i] + b[i];
}

// ---------------- mod GEMM: out[32,Nw] = cs@W + b (init + k-split atomic partials) ----------------
__global__ void mod_init(const float* __restrict__ b, float* __restrict__ out, int Nw){
  int j = blockIdx.x*256 + threadIdx.x;
  out[(size_t)blockIdx.y*Nw + j] = b[j];
}
__global__ __launch_bounds__(256)
void mod_part(const float* __restrict__ cs, const float* __restrict__ W,
              float* __restrict__ out, int Nw){
  int j  = blockIdx.x*256 + threadIdx.x;
  int k0 = blockIdx.y*256;
  __shared__ float csl[32*256];
  #pragma unroll
  for (int r=0;r<32;++r) csl[r*256 + threadIdx.x] = cs[(size_t)r*1024 + k0 + threadIdx.x];
  __syncthreads();
  float acc[32];
  #pragma unroll
  for (int r=0;r<32;++r) acc[r] = 0.f;
  for (int k=0;k<256;++k){
    float wv = W[(size_t)(k0+k)*Nw + j];
    #pragma unroll
    for (int r=0;r<32;++r) acc[r] += csl[r*256+k]*wv;
  }
  #pragma unroll
  for (int r=0;r<32;++r) atomicAdd(&out[(size_t)r*Nw + j], acc[r]);
}

// ---------------- LN(+mod) of input x, copy x -> xf ----------------
__global__ __launch_bounds__(256)
void ln_first(const float* __restrict__ xin, float* __restrict__ xf,
              const float* __restrict__ mod, int stride, int shift_off, int scale_off,
              u16* __restrict__ out){
  int tok = blockIdx.x, tid = threadIdx.x;
  float4 v = *(const float4*)(xin + (size_t)tok*1024 + tid*4);
  *(float4*)(xf + (size_t)tok*1024 + tid*4) = v;
  __shared__ float r1[256], r2[256];
  r1[tid] = v.x+v.y+v.z+v.w;
  r2[tid] = v.x*v.x+v.y*v.y+v.z*v.z+v.w*v.w;
  __syncthreads();
  for (int off=128; off>0; off>>=1){
    if (tid < off){ r1[tid] += r1[tid+off]; r2[tid] += r2[tid+off]; }
    __syncthreads();
  }
  float mean = r1[0]*(1.f/1024.f);
  float var  = r2[0]*(1.f/1024.f) - mean*mean;
  float rstd = rsqrtf(fmaxf(var,0.f) + 1e-6f);
  int bt = tok >> 8;
  const float* mr = mod + (size_t)bt*stride;
  int d = tid*4;
  float4 sh = *(const float4*)(mr + shift_off + d);
  float4 sc = *(const float4*)(mr + scale_off + d);
  float y0 = (v.x-mean)*rstd*(1.f+sc.x)+sh.x;
  float y1 = (v.y-mean)*rstd*(1.f+sc.y)+sh.y;
  float y2 = (v.z-mean)*rstd*(1.f+sc.z)+sh.z;
  float y3 = (v.w-mean)*rstd*(1.f+sc.w)+sh.w;
  uint2 ub; ub.x = pk2(y0,y1); ub.y = pk2(y2,y3);
  *(uint2*)(out + (size_t)tok*1024 + d) = ub;
}

// ---------------- fused: xf += gate*o ; then LN+mod of new xf -> h16 ----------------
__global__ __launch_bounds__(256)
void gate_ln(float* __restrict__ xf, const u16* __restrict__ o,
             const float* __restrict__ gmod, int gstride, int goff, int gperm,
             const float* __restrict__ lmod, int lstride, int shift_off, int scale_off,
             u16* __restrict__ out, int lperm){
  int tok = blockIdx.x, tid = threadIdx.x;
  int bt = tok >> 8;
  size_t stok = tok;
  if (gperm){ int b=tok>>12, t=(tok>>8)&15, ss=tok&255; stok = ((size_t)(b*256+ss)*16 + t); }
  int d = tid*4;
  uint2 u = *(const uint2*)(o + stok*1024 + d);
  float4 g = *(const float4*)(gmod + (size_t)bt*gstride + goff + d);
  float* xp = xf + (size_t)tok*1024 + d;
  float4 v = *(float4*)xp;
  v.x += bl(u.x)*g.x; v.y += bh(u.x)*g.y; v.z += bl(u.y)*g.z; v.w += bh(u.y)*g.w;
  *(float4*)xp = v;
  __shared__ float r1[256], r2[256];
  r1[tid] = v.x+v.y+v.z+v.w;
  r2[tid] = v.x*v.x+v.y*v.y+v.z*v.z+v.w*v.w;
  __syncthreads();
  for (int off=128; off>0; off>>=1){
    if (tid < off){ r1[tid] += r1[tid+off]; r2[tid] += r2[tid+off]; }
    __syncthreads();
  }
  float mean = r1[0]*(1.f/1024.f);
  float var  = r2[0]*(1.f/1024.f) - mean*mean;
  float rstd = rsqrtf(fmaxf(var,0.f) + 1e-6f);
  const float* mr = lmod + (size_t)bt*lstride;
  float4 sh = *(const float4*)(mr + shift_off + d);
  float4 sc = *(const float4*)(mr + scale_off + d);
  size_t otok = tok;
  if (lperm){ int b=tok>>12, t=(tok>>8)&15, ss=tok&255; otok = ((size_t)(b*256+ss)*16 + t); }
  float y0 = (v.x-mean)*rstd*(1.f+sc.x)+sh.x;
  float y1 = (v.y-mean)*rstd*(1.f+sc.y)+sh.y;
  float y2 = (v.z-mean)*rstd*(1.f+sc.z)+sh.z;
  float y3 = (v.w-mean)*rstd*(1.f+sc.w)+sh.w;
  uint2 ub; ub.x = pk2(y0,y1); ub.y = pk2(y2,y3);
  *(uint2*)(out + otok*1024 + d) = ub;
}

// ---------------- MFMA GEMM 128x128 (kept for N=1024 / M=512 shapes) ----------------
// KIND: 0 plain->bf16, 1 +bias(f32)->bf16, 2 +bias gelu->bf16, 3 +addend(bf16)->f32
template<int KIND>
__global__ __launch_bounds__(256, 2)
void gemm_nt(const u16* __restrict__ A, const u16* __restrict__ BT,
             u16* __restrict__ outb, float* __restrict__ outf,
             const float* __restrict__ biasf,
             const u16* __restrict__ addend, long astr,
             int M, int N, int K){
  __shared__ u16 As[128*32];
  __shared__ u16 Bs[128*32];
  const int tid  = threadIdx.x;
  const int wid  = tid >> 6, lane = tid & 63;
  const int l16  = lane & 15, quad = lane >> 4;
  const int wm   = wid >> 1,  wn   = wid & 1;
  const int m0   = blockIdx.y * 128, n0 = blockIdx.x * 128;
  f32x4 acc[4][4];
  #pragma unroll
  for (int i=0;i<4;++i)
    #pragma unroll
    for (int j=0;j<4;++j) acc[i][j] = (f32x4){0.f,0.f,0.f,0.f};

  for (int kt = 0; kt < K; kt += 32){
    __syncthreads();
    #pragma unroll
    for (int r = 0; r < 2; ++r){
      int flat = r*256 + wid*64 + lane;
      int row  = flat >> 2;          // 128 rows x 32 cols: 4 x 16B per row
      int sc   = ((flat & 3) ^ ((row >> 1) & 3)) << 3;   // pre-swizzled source chunk
      gld_lds16(&A [(size_t)(m0+row)*K + kt + sc], &As[(size_t)(r*256 + wid*64)*8]);
      gld_lds16(&BT[(size_t)(n0+row)*K + kt + sc], &Bs[(size_t)(r*256 + wid*64)*8]);
    }
    __syncthreads();
    short8 af[4], bfr[4];
    #pragma unroll
    for (int i=0;i<4;++i){
      int row = wm*64+i*16+l16;
      af[i]  = *(const short8*)&As[row*32 + ((quad ^ ((row>>1)&3))<<3)];
    }
    #pragma unroll
    for (int j=0;j<4;++j){
      int row = wn*64+j*16+l16;
      bfr[j] = *(const short8*)&Bs[row*32 + ((quad ^ ((row>>1)&3))<<3)];
    }
    #pragma unroll
    for (int i=0;i<4;++i)
      #pragma unroll
      for (int j=0;j<4;++j)
        acc[i][j] = __builtin_amdgcn_mfma_f32_16x16x32_bf16(af[i], bfr[j], acc[i][j], 0,0,0);
  }
  #pragma unroll
  for (int j=0;j<4;++j){
    int col = n0 + wn*64 + j*16 + l16;
    float bias = 0.f;
    if (KIND==1 || KIND==2) bias = biasf[col];
    #pragma unroll
    for (int i=0;i<4;++i){
      #pragma unroll
      for (int r=0;r<4;++r){
        int row = m0 + wm*64 + i*16 + quad*4 + r;
        float v = acc[i][j][r];
        if (KIND==1||KIND==2) v += bias;
        if (KIND==2) v = gelu_t(v);
        if (KIND==3){
          v += b2f(addend[(size_t)row*astr + col]);
          outf[(size_t)row*N + col] = v;
        } else {
          outb[(size_t)row*N + col] = f2b(v);
        }
      }
    }
  }
}

// ---------------- MFMA GEMM 256x256, 8 waves, deep-pipelined (T2+T3+T4+T5) ----------
// BK=32, 4-deep LDS ring (128 KiB), prefetch distance 3, counted vmcnt(8) once per
// K-tile, builtin s_barrier (NO memory-clobber asm -> no compiler waitcnt drain),
// explicit lgkmcnt(0)+sched_barrier after each barrier, setprio around MFMA.
// Ledger: end-of-tile-t vmcnt(8) retires through tile t+1 (t+2,t+3 = 8 loads stay
// in flight); buffer (t+3)&3's last reader finished >=2 barriers before the stage.
// KIND: 0 plain->bf16, 1 +bias->bf16, 2 +bias gelu->bf16
template<int KIND>
__global__ __launch_bounds__(512, 2)
void gemm256(const u16* __restrict__ A, const u16* __restrict__ BT,
             u16* __restrict__ outb, const float* __restrict__ biasf,
             int M, int N, int K){
  __shared__ u16 S[4][2][256*32];     // [buf][op A/B][row*32+col]
  const int tid  = threadIdx.x;
  const int wid  = tid >> 6, lane = tid & 63;
  const int l16  = lane & 15, quad = lane >> 4;
  const int wm   = wid >> 2,  wn   = wid & 3;       // 2M x 4N wave grid
  const int m0   = blockIdx.y * 256, n0 = blockIdx.x * 256;
  const int NT   = K >> 5;

  f32x4 acc[8][4];
  #pragma unroll
  for (int i=0;i<8;++i)
    #pragma unroll
    for (int j=0;j<4;++j) acc[i][j] = (f32x4){0.f,0.f,0.f,0.f};

  // staging geometry: 1024 16B chunks per operand per K-tile; 2 loads/thread/operand
  const int f0  = tid,        r0s = f0 >> 2;
  const int f1  = 512 + tid,  r1s = f1 >> 2;
  const int c0s = ((f0 & 3) ^ ((r0s >> 1) & 3)) << 3;   // pre-swizzled source col
  const int c1s = ((f1 & 3) ^ ((r1s >> 1) & 3)) << 3;
  const int ld0 = (wid*64)*8;          // wave-uniform LDS elem offsets
  const int ld1 = (512 + wid*64)*8;

  auto stageA = [&](int t){
    int b = t & 3, kt = t << 5;
    gld_lds16(&A[(size_t)(m0 + r0s)*K + kt + c0s], &S[b][0][ld0]);
    gld_lds16(&A[(size_t)(m0 + r1s)*K + kt + c1s], &S[b][0][ld1]);
  };
  auto stageB = [&](int t){
    int b = t & 3, kt = t << 5;
    gld_lds16(&BT[(size_t)(n0 + r0s)*K + kt + c0s], &S[b][1][ld0]);
    gld_lds16(&BT[(size_t)(n0 + r1s)*K + kt + c1s], &S[b][1][ld1]);
  };

  // prologue: stage tiles 0..2
  const int npre = NT < 3 ? NT : 3;
  for (int t=0; t<npre; ++t){ stageA(t); stageB(t); }
  if (NT >= 3)      { WAITV(8); }
  else if (NT == 2) { WAITV(4); }
  else              { WAITV(0); }
  SBAR();

  for (int t=0; t<NT; ++t){
    const int b = t & 3;
    const u16* Ab = &S[b][0][0];
    const u16* Bb = &S[b][1][0];
    short8 afr[4], bfr[4];
    // ---- phase A: issue reads (rows 0..3 of A-panel + all B frags), stage A(t+3)
    #pragma unroll
    for (int i=0;i<4;++i){
      int row = wm*128 + i*16 + l16;
      afr[i] = *(const short8*)&Ab[row*32 + ((quad ^ ((row>>1)&3))<<3)];
    }
    #pragma unroll
    for (int j=0;j<4;++j){
      int row = wn*64 + j*16 + l16;
      bfr[j] = *(const short8*)&Bb[row*32 + ((quad ^ ((row>>1)&3))<<3)];
    }
    if (t + 3 < NT) stageA(t+3);
    SBAR();
    WAITL0();
    __builtin_amdgcn_sched_barrier(0);
    __builtin_amdgcn_s_setprio(1);
    #pragma unroll
    for (int i=0;i<4;++i)
      #pragma unroll
      for (int j=0;j<4;++j)
        acc[i][j] = __builtin_amdgcn_mfma_f32_16x16x32_bf16(afr[i], bfr[j], acc[i][j], 0,0,0);
    __builtin_amdgcn_s_setprio(0);
    SBAR();
    // ---- phase B: reads (rows 4..7 of A-panel), stage B(t+3)
    short8 af2[4];
    #pragma unroll
    for (int i=0;i<4;++i){
      int row = wm*128 + (i+4)*16 + l16;
      af2[i] = *(const short8*)&Ab[row*32 + ((quad ^ ((row>>1)&3))<<3)];
    }
    if (t + 3 < NT) stageB(t+3);
    SBAR();
    WAITL0();
    __builtin_amdgcn_sched_barrier(0);
    __builtin_amdgcn_s_setprio(1);
    #pragma unroll
    for (int i=0;i<4;++i)
      #pragma unroll
      for (int j=0;j<4;++j)
        acc[i+4][j] = __builtin_amdgcn_mfma_f32_16x16x32_bf16(af2[i], bfr[j], acc[i+4][j], 0,0,0);
    __builtin_amdgcn_s_setprio(0);
    if (t + 3 < NT)      { WAITV(8); }   // tiles t+2,t+3 stay in flight
    else if (t + 2 < NT) { WAITV(4); }   // epilogue drain
    else if (t + 1 < NT) { WAITV(0); }
    SBAR();
  }

  #pragma unroll
  for (int j=0;j<4;++j){
    int col = n0 + wn*64 + j*16 + l16;
    float bias = 0.f;
    if (KIND==1 || KIND==2) bias = biasf[col];
    #pragma unroll
    for (int i=0;i<8;++i){
      #pragma unroll
      for (int r=0;r<4;++r){
        int row = m0 + wm*128 + i*16 + quad*4 + r;
        float v = acc[i][j][r];
        if (KIND==1||KIND==2) v += bias;
        if (KIND==2) v = gelu_t(v);
        outb[(size_t)row*N + col] = f2b(v);
      }
    }
  }
}

// ---------------- spatial attention, MFMA flash (block = (h,n), wave = 64 q rows) ----------------
__global__ __launch_bounds__(256)
void attn_spatial_mfma(const u16* __restrict__ qkv, u16* __restrict__ out){
  constexpr int PAD = 80;
  __shared__ u16 Ks[64*PAD];
  __shared__ u16 Vt[64*PAD];
  __shared__ u16 Ps[4*64*PAD];
  int h = blockIdx.x, n = blockIdx.y;
  int tid = threadIdx.x, wid = tid>>6, lane = tid&63, l16 = lane&15, quad = lane>>4;
  u16* Pw = Ps + wid*64*PAD;
  int qrow_base = n*256 + wid*64;
  short8 qf[4][2];
  #pragma unroll
  for (int i=0;i<4;++i)
    #pragma unroll
    for (int c=0;c<2;++c)
      qf[i][c] = *(const short8*)(qkv + (size_t)(qrow_base + i*16 + l16)*3072 + h*64 + c*32 + quad*8);
  f32x4 Oc[4][4];
  float mrun[4][4], lrun[4][4];
  #pragma unroll
  for (int i=0;i<4;++i)
    #pragma unroll
    for (int j=0;j<4;++j){ Oc[i][j] = (f32x4){0.f,0.f,0.f,0.f}; mrun[i][j] = -30000.f; lrun[i][j] = 0.f; }

  for (int kt=0; kt<4; ++kt){
    __syncthreads();
    #pragma unroll
    for (int r=0;r<2;++r){
      int flat = tid + r*256;
      int row = flat>>3, c8 = (flat&7)<<3;   // 64 rows x 64 cols: 8 x 16B per row
      const u16* kp = qkv + (size_t)(n*256 + kt*64 + row)*3072 + 1024 + h*64 + c8;
      *(short8*)&Ks[row*PAD + c8] = *(const short8*)kp;
      short8 vv = *(const short8*)(kp + 1024);
      #pragma unroll
      for (int j=0;j<8;++j) Vt[(c8+j)*PAD + row] = ((const u16*)&vv)[j];
    }
    __syncthreads();
    f32x4 S[4][4];
    #pragma unroll
    for (int i=0;i<4;++i)
      #pragma unroll
      for (int jt=0;jt<4;++jt) S[i][jt] = (f32x4){0.f,0.f,0.f,0.f};
    #pragma unroll
    for (int c=0;c<2;++c){
      short8 kf[4];
      #pragma unroll
      for (int jt=0;jt<4;++jt) kf[jt] = *(const short8*)&Ks[(jt*16+l16)*PAD + c*32 + quad*8];
      #pragma unroll
      for (int i=0;i<4;++i)
        #pragma unroll
        for (int jt=0;jt<4;++jt)
          S[i][jt] = __builtin_amdgcn_mfma_f32_16x16x32_bf16(qf[i][c], kf[jt], S[i][jt], 0,0,0);
    }
    #pragma unroll
    for (int i=0;i<4;++i){
      #pragma unroll
      for (int r=0;r<4;++r){
        float rm = -30000.f;
        #pragma unroll
        for (int jt=0;jt<4;++jt){ S[i][jt][r] *= 0.125f; rm = fmaxf(rm, S[i][jt][r]); }
        #pragma unroll
        for (int off=1; off<16; off<<=1) rm = fmaxf(rm, __shfl_xor(rm, off));
        float mnew  = fmaxf(mrun[i][r], rm);
        float alpha = __expf(mrun[i][r] - mnew);
        mrun[i][r] = mnew;
        float ps = 0.f;
        #pragma unroll
        for (int jt=0;jt<4;++jt){ float pv = __expf(S[i][jt][r] - mnew); S[i][jt][r] = pv; ps += pv; }
        #pragma unroll
        for (int off=1; off<16; off<<=1) ps += __shfl_xor(ps, off);
        lrun[i][r] = lrun[i][r]*alpha + ps;
        #pragma unroll
        for (int dt=0;dt<4;++dt) Oc[i][dt][r] *= alpha;
        #pragma unroll
        for (int jt=0;jt<4;++jt) Pw[(i*16+quad*4+r)*PAD + jt*16 + l16] = f2b(S[i][jt][r]);
      }
    }
    #pragma unroll
    for (int c=0;c<2;++c){
      short8 pf[4], vf[4];
      #pragma unroll
      for (int i=0;i<4;++i)  pf[i]  = *(const short8*)&Pw[(i*16+l16)*PAD + c*32 + quad*8];
      #pragma unroll
      for (int dt=0;dt<4;++dt) vf[dt] = *(const short8*)&Vt[(dt*16+l16)*PAD + c*32 + quad*8];
      #pragma unroll
      for (int i=0;i<4;++i)
        #pragma unroll
        for (int dt=0;dt<4;++dt)
          Oc[i][dt] = __builtin_amdgcn_mfma_f32_16x16x32_bf16(pf[i], vf[dt], Oc[i][dt], 0,0,0);
    }
  }
  #pragma unroll
  for (int i=0;i<4;++i)
    #pragma unroll
    for (int r=0;r<4;++r){
      float rl = 1.f/lrun[i][r];
      int tok = qrow_base + i*16 + quad*4 + r;
      #pragma unroll
      for (int dt=0;dt<4;++dt)
        out[(size_t)tok*1024 + h*64 + dt*16 + l16] = f2b(Oc[i][dt][r]*rl);
    }
}

// ---------------- temporal causal attention (verified VALU version) ----------------
__global__ __launch_bounds__(256, 2)
void attn_temporal(const u16* __restrict__ qkv, u16* __restrict__ out){
  int n = blockIdx.x;
  int tid = threadIdx.x;
  int h = tid>>4, q = tid&15;
  __shared__ u16 KV[16*2048];
  #pragma unroll
  for (int i=0;i<16;++i){
    int u4i = tid + i*256;
    int e = u4i*8;
    int t = e>>11, cc = e&2047;
    *(uint4*)&KV[t*2048 + cc] = *(const uint4*)(qkv + ((size_t)(n*16+t)*3072 + 1024 + cc));
  }
  __syncthreads();
  float qr[64];
  const u16* qp = qkv + ((size_t)(n*16+q)*3072 + h*64);
  #pragma unroll
  for (int i=0;i<8;++i){
    uint4 u = *(const uint4*)(qp + i*8);
    qr[i*8+0]=bl(u.x)*0.125f; qr[i*8+1]=bh(u.x)*0.125f;
    qr[i*8+2]=bl(u.y)*0.125f; qr[i*8+3]=bh(u.y)*0.125f;
    qr[i*8+4]=bl(u.z)*0.125f; qr[i*8+5]=bh(u.z)*0.125f;
    qr[i*8+6]=bl(u.w)*0.125f; qr[i*8+7]=bh(u.w)*0.125f;
  }
  float sc[16]; float m = -30000.f;
  #pragma unroll
  for (int kv=0; kv<16; ++kv){
    const uint4* kr = (const uint4*)&KV[kv*2048 + h*64];
    float s = 0.f;
    #pragma unroll
    for (int i=0;i<8;++i){
      uint4 u = kr[i];
      s += qr[i*8+0]*bl(u.x) + qr[i*8+1]*bh(u.x) + qr[i*8+2]*bl(u.y) + qr[i*8+3]*bh(u.y)
         + qr[i*8+4]*bl(u.z) + qr[i*8+5]*bh(u.z) + qr[i*8+6]*bl(u.w) + qr[i*8+7]*bh(u.w);
    }
    s = (kv<=q) ? s : -30000.f;
    sc[kv]=s; m = fmaxf(m,s);
  }
  float l=0.f, acc[64];
  #pragma unroll
  for (int d=0;d<64;++d) acc[d]=0.f;
  #pragma unroll
  for (int kv=0; kv<16; ++kv){
    float p = __expf(sc[kv]-m);
    l += p;
    const uint4* vr = (const uint4*)&KV[kv*2048 + 1024 + h*64];
    #pragma unroll
    for (int i=0;i<8;++i){
      uint4 u = vr[i];
      acc[i*8+0]+=p*bl(u.x); acc[i*8+1]+=p*bh(u.x); acc[i*8+2]+=p*bl(u.y); acc[i*8+3]+=p*bh(u.y);
      acc[i*8+4]+=p*bl(u.z); acc[i*8+5]+=p*bh(u.z); acc[i*8+6]+=p*bl(u.w); acc[i*8+7]+=p*bh(u.w);
    }
  }
  float rl = 1.f/l;
  u16* op = out + ((size_t)(n*16+q)*1024 + h*64);
  #pragma unroll
  for (int i=0;i<8;++i){
    uint4 ub;
    ub.x = pk2(acc[i*8+0]*rl, acc[i*8+1]*rl);
    ub.y = pk2(acc[i*8+2]*rl, acc[i*8+3]*rl);
    ub.z = pk2(acc[i*8+4]*rl, acc[i*8+5]*rl);
    ub.w = pk2(acc[i*8+6]*rl, acc[i*8+7]*rl);
    *(uint4*)(op + i*8) = ub;
  }
}

// ---------------- LSTM pointwise ----------------
__global__ void lstm_point(const float* __restrict__ g4, float* __restrict__ cst,
                           u16* __restrict__ hst, u16* __restrict__ hout, int t){
  size_t i4 = ((size_t)blockIdx.x*256 + threadIdx.x)*4;
  int nn = (int)(i4 >> 10);
  int d  = (int)(i4 & 1023);
  const float* g = g4 + (size_t)nn*4096 + d;
  float4 gi = *(const float4*)(g);
  float4 gf = *(const float4*)(g+1024);
  float4 gg = *(const float4*)(g+2048);
  float4 go = *(const float4*)(g+3072);
  float4 c = *(float4*)(cst + i4);
  c.x = sigm(gf.x)*c.x + sigm(gi.x)*tanh_f(gg.x);
  c.y = sigm(gf.y)*c.y + sigm(gi.y)*tanh_f(gg.y);
  c.z = sigm(gf.z)*c.z + sigm(gi.z)*tanh_f(gg.z);
  c.w = sigm(gf.w)*c.w + sigm(gi.w)*tanh_f(gg.w);
  float h0 = sigm(go.x)*tanh_f(c.x);
  float h1 = sigm(go.y)*tanh_f(c.y);
  float h2 = sigm(go.z)*tanh_f(c.z);
  float h3 = sigm(go.w)*tanh_f(c.w);
  *(float4*)(cst + i4) = c;
  uint2 hb; hb.x = pk2(h0,h1); hb.y = pk2(h2,h3);
  *(uint2*)(hst + i4) = hb;
  *(uint2*)(hout + ((size_t)nn*16 + t)*1024 + d) = hb;
}

// ---------------- final: out(f32) = xf + gate(lstm_h) ----------------
__global__ void final_out(const float* __restrict__ xf, const u16* __restrict__ hout,
                          const float* __restrict__ rmod, float* __restrict__ out){
  size_t i4 = ((size_t)blockIdx.x*256 + threadIdx.x)*4;
  int tok = (int)(i4>>10), d = (int)(i4&1023);
  int bt = tok>>8;
  int b=tok>>12, t=(tok>>8)&15, ss=tok&255;
  size_t src = (((size_t)(b*256+ss)*16 + t)*1024) + d;
  uint2 u = *(const uint2*)(hout + src);
  float4 g = *(const float4*)(rmod + (size_t)bt*3072 + 2048 + d);
  float4 x = *(const float4*)(xf + i4);
  float4 o;
  o.x = x.x + bl(u.x)*g.x; o.y = x.y + bh(u.x)*g.y;
  o.z = x.z + bl(u.y)*g.z; o.w = x.w + bh(u.y)*g.w;
  *(float4*)(out + i4) = o;
}

extern "C" void kernel_launch(void* const* d_in, const int* in_sizes, int n_in,
                              void* d_out, int out_size, void* d_ws, size_t ws_size,
                              hipStream_t stream){
  (void)in_sizes; (void)n_in; (void)out_size; (void)ws_size;
  const float* x       = (const float*)d_in[0];
  const float* c       = (const float*)d_in[1];
  const float* s_ada_w = (const float*)d_in[2];
  const float* s_ada_b = (const float*)d_in[3];
  const float* t_ada_w = (const float*)d_in[4];
  const float* t_ada_b = (const float*)d_in[5];
  const float* r_ada_w = (const float*)d_in[6];
  const float* r_ada_b = (const float*)d_in[7];
  const float* s_qkv_w = (const float*)d_in[8];
  const float* s_out_w = (const float*)d_in[9];
  const float* s_out_b = (const float*)d_in[10];
  const float* t_qkv_w = (const float*)d_in[11];
  const float* t_out_w = (const float*)d_in[12];
  const float* t_out_b = (const float*)d_in[13];
  const float* s_mlp_w1= (const float*)d_in[14];
  const float* s_mlp_b1= (const float*)d_in[15];
  const float* s_mlp_w2= (const float*)d_in[16];
  const float* s_mlp_b2= (const float*)d_in[17];
  const float* t_mlp_w1= (const float*)d_in[18];
  const float* t_mlp_b1= (const float*)d_in[19];
  const float* t_mlp_w2= (const float*)d_in[20];
  const float* t_mlp_b2= (const float*)d_in[21];
  const float* w_ih    = (const float*)d_in[22];
  const float* w_hh    = (const float*)d_in[23];
  const float* b_ih    = (const float*)d_in[24];
  const float* b_hh    = (const float*)d_in[25];

  char* p = (char*)d_ws;
  auto alloc = [&](size_t sz){ void* r = (void*)p; p += (sz + 255) & ~(size_t)255; return r; };
  float* xf    = (float*)alloc(8192ull*1024*4);
  u16*   h16   = (u16*)  alloc(8192ull*1024*2);
  u16*   big   = (u16*)  alloc(8192ull*4096*2);
  u16*   o16   = (u16*)  alloc(8192ull*1024*2);
  float* gates = (float*)alloc(512ull*4096*4);
  float* cst   = (float*)alloc(512ull*1024*4);
  u16*   hst   = (u16*)  alloc(512ull*1024*2);
  float* cs    = (float*)alloc(32ull*1024*4);
  float* smod  = (float*)alloc(32ull*6144*4);
  float* tmod  = (float*)alloc(32ull*6144*4);
  float* rmod  = (float*)alloc(32ull*3072*4);
  u16*   wT    = (u16*)  alloc(4096ull*1024*2);
  u16*   whhT  = (u16*)  alloc(4096ull*1024*2);
  float* bihh  = (float*)alloc(4096*4);

  dim3 tb(32,8);
  auto T = [&](const float* in, u16* out, int R, int C){
    transpose_f2b<<<dim3(C/32, R/32), tb, 0, stream>>>(in, out, R, C);
  };
  auto GEMM = [&](int kind, const u16* A, const u16* BT, void* out,
                  const float* b1, const u16* add, long astr, int M, int N, int K){
    dim3 g(N/128, M/128);
    switch(kind){
      case 0: gemm_nt<0><<<g,256,0,stream>>>(A,BT,(u16*)out,nullptr,nullptr,nullptr,0,M,N,K); break;
      case 1: gemm_nt<1><<<g,256,0,stream>>>(A,BT,(u16*)out,nullptr,b1,nullptr,0,M,N,K); break;
      case 2: gemm_nt<2><<<g,256,0,stream>>>(A,BT,(u16*)out,nullptr,b1,nullptr,0,M,N,K); break;
      case 3: gemm_nt<3><<<g,256,0,stream>>>(A,BT,nullptr,(float*)out,nullptr,add,astr,M,N,K); break;
    }
  };
  auto GEMM256 = [&](int kind, const u16* A, const u16* BT, u16* out,
                     const float* b1, int M, int N, int K){
    dim3 g(N/256, M/256);
    switch(kind){
      case 0: gemm256<0><<<g,512,0,stream>>>(A,BT,out,nullptr,M,N,K); break;
      case 1: gemm256<1><<<g,512,0,stream>>>(A,BT,out,b1,M,N,K); break;
      case 2: gemm256<2><<<g,512,0,stream>>>(A,BT,out,b1,M,N,K); break;
    }
  };
  auto MOD = [&](const float* W, const float* b, float* out, int Nw){
    mod_init<<<dim3(Nw/256,32),256,0,stream>>>(b, out, Nw);
    mod_part<<<dim3(Nw/256,4),256,0,stream>>>(cs, W, out, Nw);
  };

  silu_k<<<128,256,0,stream>>>(c, cs);
  MOD(s_ada_w, s_ada_b, smod, 6144);
  MOD(t_ada_w, t_ada_b, tmod, 6144);
  MOD(r_ada_w, r_ada_b, rmod, 3072);
  add_bias<<<16,256,0,stream>>>(b_ih, b_hh, bihh);

  // ---- spatial attention
  ln_first<<<8192,256,0,stream>>>(x, xf, smod, 6144, 0, 1024, h16);
  T(s_qkv_w, wT, 1024, 3072);
  GEMM256(0, h16, wT, big, nullptr, 8192, 3072, 1024);
  attn_spatial_mfma<<<dim3(16,32),256,0,stream>>>(big, h16);
  T(s_out_w, wT, 1024, 1024);
  GEMM(1, h16, wT, o16, s_out_b, nullptr, 0, 8192, 1024, 1024);
  gate_ln<<<8192,256,0,stream>>>(xf, o16, smod, 6144, 2048, 0, smod, 6144, 3072, 4096, h16, 0);
  // ---- spatial MLP
  T(s_mlp_w1, wT, 1024, 4096);
  GEMM256(2, h16, wT, big, s_mlp_b1, 8192, 4096, 1024);
  T(s_mlp_w2, wT, 4096, 1024);
  GEMM(1, big, wT, o16, s_mlp_b2, nullptr, 0, 8192, 1024, 4096);
  gate_ln<<<8192,256,0,stream>>>(xf, o16, smod, 6144, 5120, 0, tmod, 6144, 0, 1024, h16, 1);
  // ---- temporal attention
  T(t_qkv_w, wT, 1024, 3072);
  GEMM256(0, h16, wT, big, nullptr, 8192, 3072, 1024);
  attn_temporal<<<512,256,0,stream>>>(big, h16);
  T(t_out_w, wT, 1024, 1024);
  GEMM(1, h16, wT, o16, t_out_b, nullptr, 0, 8192, 1024, 1024);
  gate_ln<<<8192,256,0,stream>>>(xf, o16, tmod, 6144, 2048, 1, tmod, 6144, 3072, 4096, h16, 0);
  // ---- temporal MLP
  T(t_mlp_w1, wT, 1024, 4096);
  GEMM256(2, h16, wT, big, t_mlp_b1, 8192, 4096, 1024);
  T(t_mlp_w2, wT, 4096, 1024);
  GEMM(1, big, wT, o16, t_mlp_b2, nullptr, 0, 8192, 1024, 4096);
  gate_ln<<<8192,256,0,stream>>>(xf, o16, tmod, 6144, 5120, 0, rmod, 3072, 0, 1024, h16, 1);
  // ---- LSTM branch
  T(w_ih, wT, 1024, 4096);
  GEMM256(1, h16, wT, big, bihh, 8192, 4096, 1024);
  T(w_hh, whhT, 1024, 4096);
  hipMemsetAsync(cst, 0, 512ull*1024*4, stream);
  hipMemsetAsync(hst, 0, 512ull*1024*2, stream);
  for (int t=0; t<16; ++t){
    GEMM(3, hst, whhT, gates, nullptr, big + (size_t)t*4096, 16*4096, 512, 4096, 1024);
    lstm_point<<<512,256,0,stream>>>(gates, cst, hst, o16, t);
  }
  final_out<<<8192,256,0,stream>>>(xf, o16, rmod, (float*)d_out);
}

// Round 4
// 1978.024 us; speedup vs baseline: 1.0659x; 1.0659x over previous
//
#include <hip/hip_runtime.h>
#include <hip/hip_bf16.h>
#include <stdint.h>

typedef unsigned short u16;
typedef unsigned int u32;
typedef short short8 __attribute__((ext_vector_type(8)));
typedef float f32x4 __attribute__((ext_vector_type(4)));

// Verified m201 sync idiom: builtin barrier (no implicit waitcnt drain),
// clobber-free waitcnt asm. A "memory" clobber here makes the backend emit
// s_waitcnt vmcnt(0) lgkmcnt(0) before the asm -> kills the pipeline.
// NO sched_barrier(0): it pins the schedule and costs ~40% (m141).
#define SBAR()   __builtin_amdgcn_s_barrier()
#define WAITV(n) asm volatile("s_waitcnt vmcnt(" #n ")")
#define WAITL0() asm volatile("s_waitcnt lgkmcnt(0)")

__device__ __forceinline__ float bl(u32 x){ return __uint_as_float(x<<16); }
__device__ __forceinline__ float bh(u32 x){ return __uint_as_float(x & 0xffff0000u); }
__device__ __forceinline__ float b2f(u16 x){ return __uint_as_float(((u32)x)<<16); }
__device__ __forceinline__ u16 f2b(float f){
  u32 u = __float_as_uint(f);
  u32 r = (u + 0x7fffu + ((u>>16)&1u)) >> 16;
  return (u16)r;
}
__device__ __forceinline__ u32 pk2(float a, float b){ return (u32)f2b(a) | ((u32)f2b(b)<<16); }
__device__ __forceinline__ float tanh_f(float x){ return 1.f - 2.f/(__expf(2.f*x)+1.f); }
__device__ __forceinline__ float sigm(float x){ return 1.f/(1.f+__expf(-x)); }
__device__ __forceinline__ float gelu_t(float x){
  float u = 0.7978845608028654f*(x + 0.044715f*x*x*x);
  return 0.5f*x*(1.f + tanh_f(u));
}
// async global->LDS, 16B per lane; lds base must be wave-uniform
__device__ __forceinline__ void gld_lds16(const u16* g, u16* lds_base){
  __builtin_amdgcn_global_load_lds((const __attribute__((address_space(1))) void*)g,
                                   (__attribute__((address_space(3))) void*)lds_base,
                                   16, 0, 0);
}

// ---------------- transpose f32 [R,C] -> bf16 [C,R] ----------------
__global__ void transpose_f2b(const float* __restrict__ in, u16* __restrict__ out, int R, int C){
  __shared__ u16 t[32][33];
  int c0 = blockIdx.x*32, r0 = blockIdx.y*32;
  int tx = threadIdx.x, ty = threadIdx.y;   // 32 x 8
  #pragma unroll
  for (int i=0;i<4;++i) t[ty+i*8][tx] = f2b(in[(size_t)(r0+ty+i*8)*C + c0+tx]);
  __syncthreads();
  #pragma unroll
  for (int i=0;i<4;++i) out[(size_t)(c0+ty+i*8)*R + r0+tx] = t[tx][ty+i*8];
}

// ---------------- silu ----------------
__global__ void silu_k(const float* __restrict__ c, float* __restrict__ cs){
  int i = blockIdx.x*256 + threadIdx.x;
  float v = c[i];
  cs[i] = v * sigm(v);
}

// ---------------- b_ih + b_hh ----------------
__global__ void add_bias(const float* __restrict__ a, const float* __restrict__ b,
                         float* __restrict__ o){
  int i = blockIdx.x*256 + threadIdx.x;
  o[i] = a[i] + b[i];
}

// ---------------- mod GEMM: out[32,Nw] = cs@W + b (init + k-split atomic partials) ----------------
__global__ void mod_init(const float* __restrict__ b, float* __restrict__ out, int Nw){
  int j = blockIdx.x*256 + threadIdx.x;
  out[(size_t)blockIdx.y*Nw + j] = b[j];
}
__global__ __launch_bounds__(256)
void mod_part(const float* __restrict__ cs, const float* __restrict__ W,
              float* __restrict__ out, int Nw){
  int j  = blockIdx.x*256 + threadIdx.x;
  int k0 = blockIdx.y*256;
  __shared__ float csl[32*256];
  #pragma unroll
  for (int r=0;r<32;++r) csl[r*256 + threadIdx.x] = cs[(size_t)r*1024 + k0 + threadIdx.x];
  __syncthreads();
  float acc[32];
  #pragma unroll
  for (int r=0;r<32;++r) acc[r] = 0.f;
  for (int k=0;k<256;++k){
    float wv = W[(size_t)(k0+k)*Nw + j];
    #pragma unroll
    for (int r=0;r<32;++r) acc[r] += csl[r*256+k]*wv;
  }
  #pragma unroll
  for (int r=0;r<32;++r) atomicAdd(&out[(size_t)r*Nw + j], acc[r]);
}

// ---------------- LN(+mod) of input x, copy x -> xf ----------------
__global__ __launch_bounds__(256)
void ln_first(const float* __restrict__ xin, float* __restrict__ xf,
              const float* __restrict__ mod, int stride, int shift_off, int scale_off,
              u16* __restrict__ out){
  int tok = blockIdx.x, tid = threadIdx.x;
  float4 v = *(const float4*)(xin + (size_t)tok*1024 + tid*4);
  *(float4*)(xf + (size_t)tok*1024 + tid*4) = v;
  __shared__ float r1[256], r2[256];
  r1[tid] = v.x+v.y+v.z+v.w;
  r2[tid] = v.x*v.x+v.y*v.y+v.z*v.z+v.w*v.w;
  __syncthreads();
  for (int off=128; off>0; off>>=1){
    if (tid < off){ r1[tid] += r1[tid+off]; r2[tid] += r2[tid+off]; }
    __syncthreads();
  }
  float mean = r1[0]*(1.f/1024.f);
  float var  = r2[0]*(1.f/1024.f) - mean*mean;
  float rstd = rsqrtf(fmaxf(var,0.f) + 1e-6f);
  int bt = tok >> 8;
  const float* mr = mod + (size_t)bt*stride;
  int d = tid*4;
  float4 sh = *(const float4*)(mr + shift_off + d);
  float4 sc = *(const float4*)(mr + scale_off + d);
  float y0 = (v.x-mean)*rstd*(1.f+sc.x)+sh.x;
  float y1 = (v.y-mean)*rstd*(1.f+sc.y)+sh.y;
  float y2 = (v.z-mean)*rstd*(1.f+sc.z)+sh.z;
  float y3 = (v.w-mean)*rstd*(1.f+sc.w)+sh.w;
  uint2 ub; ub.x = pk2(y0,y1); ub.y = pk2(y2,y3);
  *(uint2*)(out + (size_t)tok*1024 + d) = ub;
}

// ---------------- fused: xf += gate*o ; then LN+mod of new xf -> h16 ----------------
__global__ __launch_bounds__(256)
void gate_ln(float* __restrict__ xf, const u16* __restrict__ o,
             const float* __restrict__ gmod, int gstride, int goff, int gperm,
             const float* __restrict__ lmod, int lstride, int shift_off, int scale_off,
             u16* __restrict__ out, int lperm){
  int tok = blockIdx.x, tid = threadIdx.x;
  int bt = tok >> 8;
  size_t stok = tok;
  if (gperm){ int b=tok>>12, t=(tok>>8)&15, ss=tok&255; stok = ((size_t)(b*256+ss)*16 + t); }
  int d = tid*4;
  uint2 u = *(const uint2*)(o + stok*1024 + d);
  float4 g = *(const float4*)(gmod + (size_t)bt*gstride + goff + d);
  float* xp = xf + (size_t)tok*1024 + d;
  float4 v = *(float4*)xp;
  v.x += bl(u.x)*g.x; v.y += bh(u.x)*g.y; v.z += bl(u.y)*g.z; v.w += bh(u.y)*g.w;
  *(float4*)xp = v;
  __shared__ float r1[256], r2[256];
  r1[tid] = v.x+v.y+v.z+v.w;
  r2[tid] = v.x*v.x+v.y*v.y+v.z*v.z+v.w*v.w;
  __syncthreads();
  for (int off=128; off>0; off>>=1){
    if (tid < off){ r1[tid] += r1[tid+off]; r2[tid] += r2[tid+off]; }
    __syncthreads();
  }
  float mean = r1[0]*(1.f/1024.f);
  float var  = r2[0]*(1.f/1024.f) - mean*mean;
  float rstd = rsqrtf(fmaxf(var,0.f) + 1e-6f);
  const float* mr = lmod + (size_t)bt*lstride;
  float4 sh = *(const float4*)(mr + shift_off + d);
  float4 sc = *(const float4*)(mr + scale_off + d);
  size_t otok = tok;
  if (lperm){ int b=tok>>12, t=(tok>>8)&15, ss=tok&255; otok = ((size_t)(b*256+ss)*16 + t); }
  float y0 = (v.x-mean)*rstd*(1.f+sc.x)+sh.x;
  float y1 = (v.y-mean)*rstd*(1.f+sc.y)+sh.y;
  float y2 = (v.z-mean)*rstd*(1.f+sc.z)+sh.z;
  float y3 = (v.w-mean)*rstd*(1.f+sc.w)+sh.w;
  uint2 ub; ub.x = pk2(y0,y1); ub.y = pk2(y2,y3);
  *(uint2*)(out + otok*1024 + d) = ub;
}

// ---------------- MFMA GEMM 128x128 (kept for N=1024 / M=512 shapes) ----------------
// KIND: 0 plain->bf16, 1 +bias(f32)->bf16, 2 +bias gelu->bf16, 3 +addend(bf16)->f32
template<int KIND>
__global__ __launch_bounds__(256, 2)
void gemm_nt(const u16* __restrict__ A, const u16* __restrict__ BT,
             u16* __restrict__ outb, float* __restrict__ outf,
             const float* __restrict__ biasf,
             const u16* __restrict__ addend, long astr,
             int M, int N, int K){
  __shared__ u16 As[128*32];
  __shared__ u16 Bs[128*32];
  const int tid  = threadIdx.x;
  const int wid  = tid >> 6, lane = tid & 63;
  const int l16  = lane & 15, quad = lane >> 4;
  const int wm   = wid >> 1,  wn   = wid & 1;
  const int m0   = blockIdx.y * 128, n0 = blockIdx.x * 128;
  f32x4 acc[4][4];
  #pragma unroll
  for (int i=0;i<4;++i)
    #pragma unroll
    for (int j=0;j<4;++j) acc[i][j] = (f32x4){0.f,0.f,0.f,0.f};

  for (int kt = 0; kt < K; kt += 32){
    __syncthreads();
    #pragma unroll
    for (int r = 0; r < 2; ++r){
      int flat = r*256 + wid*64 + lane;
      int row  = flat >> 2;          // 128 rows x 32 cols: 4 x 16B per row
      int sc   = ((flat & 3) ^ ((row >> 1) & 3)) << 3;   // pre-swizzled source chunk
      gld_lds16(&A [(size_t)(m0+row)*K + kt + sc], &As[(size_t)(r*256 + wid*64)*8]);
      gld_lds16(&BT[(size_t)(n0+row)*K + kt + sc], &Bs[(size_t)(r*256 + wid*64)*8]);
    }
    __syncthreads();
    short8 af[4], bfr[4];
    #pragma unroll
    for (int i=0;i<4;++i){
      int row = wm*64+i*16+l16;
      af[i]  = *(const short8*)&As[row*32 + ((quad ^ ((row>>1)&3))<<3)];
    }
    #pragma unroll
    for (int j=0;j<4;++j){
      int row = wn*64+j*16+l16;
      bfr[j] = *(const short8*)&Bs[row*32 + ((quad ^ ((row>>1)&3))<<3)];
    }
    #pragma unroll
    for (int i=0;i<4;++i)
      #pragma unroll
      for (int j=0;j<4;++j)
        acc[i][j] = __builtin_amdgcn_mfma_f32_16x16x32_bf16(af[i], bfr[j], acc[i][j], 0,0,0);
  }
  #pragma unroll
  for (int j=0;j<4;++j){
    int col = n0 + wn*64 + j*16 + l16;
    float bias = 0.f;
    if (KIND==1 || KIND==2) bias = biasf[col];
    #pragma unroll
    for (int i=0;i<4;++i){
      #pragma unroll
      for (int r=0;r<4;++r){
        int row = m0 + wm*64 + i*16 + quad*4 + r;
        float v = acc[i][j][r];
        if (KIND==1||KIND==2) v += bias;
        if (KIND==2) v = gelu_t(v);
        if (KIND==3){
          v += b2f(addend[(size_t)row*astr + col]);
          outf[(size_t)row*N + col] = v;
        } else {
          outb[(size_t)row*N + col] = f2b(v);
        }
      }
    }
  }
}

// ---------------- MFMA GEMM 256x256, 8 waves, deep-pipelined (T2+T3+T4+T5) ----------
// BK=32, 4-deep LDS ring (128 KiB), prefetch distance 3, counted vmcnt(8) once per
// K-tile, builtin s_barrier (no waitcnt drain), clobber-free lgkmcnt(0) before the
// MFMA cluster, setprio around MFMA. NO sched_barrier (m141: pins schedule, -40%).
// Ledger: end-of-tile-t vmcnt(8) retires through tile t+1 (t+2,t+3 = 8 loads stay
// in flight); buffer (t+3)&3's last reader finished >=2 barriers before the stage.
// KIND: 0 plain->bf16, 1 +bias->bf16, 2 +bias gelu->bf16
template<int KIND>
__global__ __launch_bounds__(512, 2)
void gemm256(const u16* __restrict__ A, const u16* __restrict__ BT,
             u16* __restrict__ outb, const float* __restrict__ biasf,
             int M, int N, int K){
  __shared__ u16 S[4][2][256*32];     // [buf][op A/B][row*32+col]
  const int tid  = threadIdx.x;
  const int wid  = tid >> 6, lane = tid & 63;
  const int l16  = lane & 15, quad = lane >> 4;
  const int wm   = wid >> 2,  wn   = wid & 3;       // 2M x 4N wave grid
  const int m0   = blockIdx.y * 256, n0 = blockIdx.x * 256;
  const int NT   = K >> 5;

  f32x4 acc[8][4];
  #pragma unroll
  for (int i=0;i<8;++i)
    #pragma unroll
    for (int j=0;j<4;++j) acc[i][j] = (f32x4){0.f,0.f,0.f,0.f};

  // staging geometry: 1024 16B chunks per operand per K-tile; 2 loads/thread/operand
  const int f0  = tid,        r0s = f0 >> 2;
  const int f1  = 512 + tid,  r1s = f1 >> 2;
  const int c0s = ((f0 & 3) ^ ((r0s >> 1) & 3)) << 3;   // pre-swizzled source col
  const int c1s = ((f1 & 3) ^ ((r1s >> 1) & 3)) << 3;
  const int ld0 = (wid*64)*8;          // wave-uniform LDS elem offsets
  const int ld1 = (512 + wid*64)*8;

  auto stageA = [&](int t){
    int b = t & 3, kt = t << 5;
    gld_lds16(&A[(size_t)(m0 + r0s)*K + kt + c0s], &S[b][0][ld0]);
    gld_lds16(&A[(size_t)(m0 + r1s)*K + kt + c1s], &S[b][0][ld1]);
  };
  auto stageB = [&](int t){
    int b = t & 3, kt = t << 5;
    gld_lds16(&BT[(size_t)(n0 + r0s)*K + kt + c0s], &S[b][1][ld0]);
    gld_lds16(&BT[(size_t)(n0 + r1s)*K + kt + c1s], &S[b][1][ld1]);
  };

  // prologue: stage tiles 0..2
  const int npre = NT < 3 ? NT : 3;
  for (int t=0; t<npre; ++t){ stageA(t); stageB(t); }
  if (NT >= 3)      { WAITV(8); }
  else if (NT == 2) { WAITV(4); }
  else              { WAITV(0); }
  SBAR();

  for (int t=0; t<NT; ++t){
    const int b = t & 3;
    const u16* Ab = &S[b][0][0];
    const u16* Bb = &S[b][1][0];
    short8 afr[4], bfr[4];
    // ---- phase A: issue reads (rows 0..3 of A-panel + all B frags), stage A(t+3)
    #pragma unroll
    for (int i=0;i<4;++i){
      int row = wm*128 + i*16 + l16;
      afr[i] = *(const short8*)&Ab[row*32 + ((quad ^ ((row>>1)&3))<<3)];
    }
    #pragma unroll
    for (int j=0;j<4;++j){
      int row = wn*64 + j*16 + l16;
      bfr[j] = *(const short8*)&Bb[row*32 + ((quad ^ ((row>>1)&3))<<3)];
    }
    if (t + 3 < NT) stageA(t+3);
    SBAR();
    WAITL0();
    __builtin_amdgcn_s_setprio(1);
    #pragma unroll
    for (int i=0;i<4;++i)
      #pragma unroll
      for (int j=0;j<4;++j)
        acc[i][j] = __builtin_amdgcn_mfma_f32_16x16x32_bf16(afr[i], bfr[j], acc[i][j], 0,0,0);
    __builtin_amdgcn_s_setprio(0);
    SBAR();
    // ---- phase B: reads (rows 4..7 of A-panel), stage B(t+3)
    short8 af2[4];
    #pragma unroll
    for (int i=0;i<4;++i){
      int row = wm*128 + (i+4)*16 + l16;
      af2[i] = *(const short8*)&Ab[row*32 + ((quad ^ ((row>>1)&3))<<3)];
    }
    if (t + 3 < NT) stageB(t+3);
    SBAR();
    WAITL0();
    __builtin_amdgcn_s_setprio(1);
    #pragma unroll
    for (int i=0;i<4;++i)
      #pragma unroll
      for (int j=0;j<4;++j)
        acc[i+4][j] = __builtin_amdgcn_mfma_f32_16x16x32_bf16(af2[i], bfr[j], acc[i+4][j], 0,0,0);
    __builtin_amdgcn_s_setprio(0);
    if (t + 3 < NT)      { WAITV(8); }   // tiles t+2,t+3 stay in flight
    else if (t + 2 < NT) { WAITV(4); }   // epilogue drain
    else if (t + 1 < NT) { WAITV(0); }
    SBAR();
  }

  #pragma unroll
  for (int j=0;j<4;++j){
    int col = n0 + wn*64 + j*16 + l16;
    float bias = 0.f;
    if (KIND==1 || KIND==2) bias = biasf[col];
    #pragma unroll
    for (int i=0;i<8;++i){
      #pragma unroll
      for (int r=0;r<4;++r){
        int row = m0 + wm*128 + i*16 + quad*4 + r;
        float v = acc[i][j][r];
        if (KIND==1||KIND==2) v += bias;
        if (KIND==2) v = gelu_t(v);
        outb[(size_t)row*N + col] = f2b(v);
      }
    }
  }
}

// ---------------- spatial attention, MFMA flash (block = (h,n), wave = 64 q rows) ----------------
__global__ __launch_bounds__(256)
void attn_spatial_mfma(const u16* __restrict__ qkv, u16* __restrict__ out){
  constexpr int PAD = 80;
  __shared__ u16 Ks[64*PAD];
  __shared__ u16 Vt[64*PAD];
  __shared__ u16 Ps[4*64*PAD];
  int h = blockIdx.x, n = blockIdx.y;
  int tid = threadIdx.x, wid = tid>>6, lane = tid&63, l16 = lane&15, quad = lane>>4;
  u16* Pw = Ps + wid*64*PAD;
  int qrow_base = n*256 + wid*64;
  short8 qf[4][2];
  #pragma unroll
  for (int i=0;i<4;++i)
    #pragma unroll
    for (int c=0;c<2;++c)
      qf[i][c] = *(const short8*)(qkv + (size_t)(qrow_base + i*16 + l16)*3072 + h*64 + c*32 + quad*8);
  f32x4 Oc[4][4];
  float mrun[4][4], lrun[4][4];
  #pragma unroll
  for (int i=0;i<4;++i)
    #pragma unroll
    for (int j=0;j<4;++j){ Oc[i][j] = (f32x4){0.f,0.f,0.f,0.f}; mrun[i][j] = -30000.f; lrun[i][j] = 0.f; }

  for (int kt=0; kt<4; ++kt){
    __syncthreads();
    #pragma unroll
    for (int r=0;r<2;++r){
      int flat = tid + r*256;
      int row = flat>>3, c8 = (flat&7)<<3;   // 64 rows x 64 cols: 8 x 16B per row
      const u16* kp = qkv + (size_t)(n*256 + kt*64 + row)*3072 + 1024 + h*64 + c8;
      *(short8*)&Ks[row*PAD + c8] = *(const short8*)kp;
      short8 vv = *(const short8*)(kp + 1024);
      #pragma unroll
      for (int j=0;j<8;++j) Vt[(c8+j)*PAD + row] = ((const u16*)&vv)[j];
    }
    __syncthreads();
    f32x4 S[4][4];
    #pragma unroll
    for (int i=0;i<4;++i)
      #pragma unroll
      for (int jt=0;jt<4;++jt) S[i][jt] = (f32x4){0.f,0.f,0.f,0.f};
    #pragma unroll
    for (int c=0;c<2;++c){
      short8 kf[4];
      #pragma unroll
      for (int jt=0;jt<4;++jt) kf[jt] = *(const short8*)&Ks[(jt*16+l16)*PAD + c*32 + quad*8];
      #pragma unroll
      for (int i=0;i<4;++i)
        #pragma unroll
        for (int jt=0;jt<4;++jt)
          S[i][jt] = __builtin_amdgcn_mfma_f32_16x16x32_bf16(qf[i][c], kf[jt], S[i][jt], 0,0,0);
    }
    #pragma unroll
    for (int i=0;i<4;++i){
      #pragma unroll
      for (int r=0;r<4;++r){
        float rm = -30000.f;
        #pragma unroll
        for (int jt=0;jt<4;++jt){ S[i][jt][r] *= 0.125f; rm = fmaxf(rm, S[i][jt][r]); }
        #pragma unroll
        for (int off=1; off<16; off<<=1) rm = fmaxf(rm, __shfl_xor(rm, off));
        float mnew  = fmaxf(mrun[i][r], rm);
        float alpha = __expf(mrun[i][r] - mnew);
        mrun[i][r] = mnew;
        float ps = 0.f;
        #pragma unroll
        for (int jt=0;jt<4;++jt){ float pv = __expf(S[i][jt][r] - mnew); S[i][jt][r] = pv; ps += pv; }
        #pragma unroll
        for (int off=1; off<16; off<<=1) ps += __shfl_xor(ps, off);
        lrun[i][r] = lrun[i][r]*alpha + ps;
        #pragma unroll
        for (int dt=0;dt<4;++dt) Oc[i][dt][r] *= alpha;
        #pragma unroll
        for (int jt=0;jt<4;++jt) Pw[(i*16+quad*4+r)*PAD + jt*16 + l16] = f2b(S[i][jt][r]);
      }
    }
    #pragma unroll
    for (int c=0;c<2;++c){
      short8 pf[4], vf[4];
      #pragma unroll
      for (int i=0;i<4;++i)  pf[i]  = *(const short8*)&Pw[(i*16+l16)*PAD + c*32 + quad*8];
      #pragma unroll
      for (int dt=0;dt<4;++dt) vf[dt] = *(const short8*)&Vt[(dt*16+l16)*PAD + c*32 + quad*8];
      #pragma unroll
      for (int i=0;i<4;++i)
        #pragma unroll
        for (int dt=0;dt<4;++dt)
          Oc[i][dt] = __builtin_amdgcn_mfma_f32_16x16x32_bf16(pf[i], vf[dt], Oc[i][dt], 0,0,0);
    }
  }
  #pragma unroll
  for (int i=0;i<4;++i)
    #pragma unroll
    for (int r=0;r<4;++r){
      float rl = 1.f/lrun[i][r];
      int tok = qrow_base + i*16 + quad*4 + r;
      #pragma unroll
      for (int dt=0;dt<4;++dt)
        out[(size_t)tok*1024 + h*64 + dt*16 + l16] = f2b(Oc[i][dt][r]*rl);
    }
}

// ---------------- temporal causal attention (verified VALU version) ----------------
__global__ __launch_bounds__(256, 2)
void attn_temporal(const u16* __restrict__ qkv, u16* __restrict__ out){
  int n = blockIdx.x;
  int tid = threadIdx.x;
  int h = tid>>4, q = tid&15;
  __shared__ u16 KV[16*2048];
  #pragma unroll
  for (int i=0;i<16;++i){
    int u4i = tid + i*256;
    int e = u4i*8;
    int t = e>>11, cc = e&2047;
    *(uint4*)&KV[t*2048 + cc] = *(const uint4*)(qkv + ((size_t)(n*16+t)*3072 + 1024 + cc));
  }
  __syncthreads();
  float qr[64];
  const u16* qp = qkv + ((size_t)(n*16+q)*3072 + h*64);
  #pragma unroll
  for (int i=0;i<8;++i){
    uint4 u = *(const uint4*)(qp + i*8);
    qr[i*8+0]=bl(u.x)*0.125f; qr[i*8+1]=bh(u.x)*0.125f;
    qr[i*8+2]=bl(u.y)*0.125f; qr[i*8+3]=bh(u.y)*0.125f;
    qr[i*8+4]=bl(u.z)*0.125f; qr[i*8+5]=bh(u.z)*0.125f;
    qr[i*8+6]=bl(u.w)*0.125f; qr[i*8+7]=bh(u.w)*0.125f;
  }
  float sc[16]; float m = -30000.f;
  #pragma unroll
  for (int kv=0; kv<16; ++kv){
    const uint4* kr = (const uint4*)&KV[kv*2048 + h*64];
    float s = 0.f;
    #pragma unroll
    for (int i=0;i<8;++i){
      uint4 u = kr[i];
      s += qr[i*8+0]*bl(u.x) + qr[i*8+1]*bh(u.x) + qr[i*8+2]*bl(u.y) + qr[i*8+3]*bh(u.y)
         + qr[i*8+4]*bl(u.z) + qr[i*8+5]*bh(u.z) + qr[i*8+6]*bl(u.w) + qr[i*8+7]*bh(u.w);
    }
    s = (kv<=q) ? s : -30000.f;
    sc[kv]=s; m = fmaxf(m,s);
  }
  float l=0.f, acc[64];
  #pragma unroll
  for (int d=0;d<64;++d) acc[d]=0.f;
  #pragma unroll
  for (int kv=0; kv<16; ++kv){
    float p = __expf(sc[kv]-m);
    l += p;
    const uint4* vr = (const uint4*)&KV[kv*2048 + 1024 + h*64];
    #pragma unroll
    for (int i=0;i<8;++i){
      uint4 u = vr[i];
      acc[i*8+0]+=p*bl(u.x); acc[i*8+1]+=p*bh(u.x); acc[i*8+2]+=p*bl(u.y); acc[i*8+3]+=p*bh(u.y);
      acc[i*8+4]+=p*bl(u.z); acc[i*8+5]+=p*bh(u.z); acc[i*8+6]+=p*bl(u.w); acc[i*8+7]+=p*bh(u.w);
    }
  }
  float rl = 1.f/l;
  u16* op = out + ((size_t)(n*16+q)*1024 + h*64);
  #pragma unroll
  for (int i=0;i<8;++i){
    uint4 ub;
    ub.x = pk2(acc[i*8+0]*rl, acc[i*8+1]*rl);
    ub.y = pk2(acc[i*8+2]*rl, acc[i*8+3]*rl);
    ub.z = pk2(acc[i*8+4]*rl, acc[i*8+5]*rl);
    ub.w = pk2(acc[i*8+6]*rl, acc[i*8+7]*rl);
    *(uint4*)(op + i*8) = ub;
  }
}

// ---------------- LSTM pointwise ----------------
__global__ void lstm_point(const float* __restrict__ g4, float* __restrict__ cst,
                           u16* __restrict__ hst, u16* __restrict__ hout, int t){
  size_t i4 = ((size_t)blockIdx.x*256 + threadIdx.x)*4;
  int nn = (int)(i4 >> 10);
  int d  = (int)(i4 & 1023);
  const float* g = g4 + (size_t)nn*4096 + d;
  float4 gi = *(const float4*)(g);
  float4 gf = *(const float4*)(g+1024);
  float4 gg = *(const float4*)(g+2048);
  float4 go = *(const float4*)(g+3072);
  float4 c = *(float4*)(cst + i4);
  c.x = sigm(gf.x)*c.x + sigm(gi.x)*tanh_f(gg.x);
  c.y = sigm(gf.y)*c.y + sigm(gi.y)*tanh_f(gg.y);
  c.z = sigm(gf.z)*c.z + sigm(gi.z)*tanh_f(gg.z);
  c.w = sigm(gf.w)*c.w + sigm(gi.w)*tanh_f(gg.w);
  float h0 = sigm(go.x)*tanh_f(c.x);
  float h1 = sigm(go.y)*tanh_f(c.y);
  float h2 = sigm(go.z)*tanh_f(c.z);
  float h3 = sigm(go.w)*tanh_f(c.w);
  *(float4*)(cst + i4) = c;
  uint2 hb; hb.x = pk2(h0,h1); hb.y = pk2(h2,h3);
  *(uint2*)(hst + i4) = hb;
  *(uint2*)(hout + ((size_t)nn*16 + t)*1024 + d) = hb;
}

// ---------------- final: out(f32) = xf + gate(lstm_h) ----------------
__global__ void final_out(const float* __restrict__ xf, const u16* __restrict__ hout,
                          const float* __restrict__ rmod, float* __restrict__ out){
  size_t i4 = ((size_t)blockIdx.x*256 + threadIdx.x)*4;
  int tok = (int)(i4>>10), d = (int)(i4&1023);
  int bt = tok>>8;
  int b=tok>>12, t=(tok>>8)&15, ss=tok&255;
  size_t src = (((size_t)(b*256+ss)*16 + t)*1024) + d;
  uint2 u = *(const uint2*)(hout + src);
  float4 g = *(const float4*)(rmod + (size_t)bt*3072 + 2048 + d);
  float4 x = *(const float4*)(xf + i4);
  float4 o;
  o.x = x.x + bl(u.x)*g.x; o.y = x.y + bh(u.x)*g.y;
  o.z = x.z + bl(u.y)*g.z; o.w = x.w + bh(u.y)*g.w;
  *(float4*)(out + i4) = o;
}

extern "C" void kernel_launch(void* const* d_in, const int* in_sizes, int n_in,
                              void* d_out, int out_size, void* d_ws, size_t ws_size,
                              hipStream_t stream){
  (void)in_sizes; (void)n_in; (void)out_size; (void)ws_size;
  const float* x       = (const float*)d_in[0];
  const float* c       = (const float*)d_in[1];
  const float* s_ada_w = (const float*)d_in[2];
  const float* s_ada_b = (const float*)d_in[3];
  const float* t_ada_w = (const float*)d_in[4];
  const float* t_ada_b = (const float*)d_in[5];
  const float* r_ada_w = (const float*)d_in[6];
  const float* r_ada_b = (const float*)d_in[7];
  const float* s_qkv_w = (const float*)d_in[8];
  const float* s_out_w = (const float*)d_in[9];
  const float* s_out_b = (const float*)d_in[10];
  const float* t_qkv_w = (const float*)d_in[11];
  const float* t_out_w = (const float*)d_in[12];
  const float* t_out_b = (const float*)d_in[13];
  const float* s_mlp_w1= (const float*)d_in[14];
  const float* s_mlp_b1= (const float*)d_in[15];
  const float* s_mlp_w2= (const float*)d_in[16];
  const float* s_mlp_b2= (const float*)d_in[17];
  const float* t_mlp_w1= (const float*)d_in[18];
  const float* t_mlp_b1= (const float*)d_in[19];
  const float* t_mlp_w2= (const float*)d_in[20];
  const float* t_mlp_b2= (const float*)d_in[21];
  const float* w_ih    = (const float*)d_in[22];
  const float* w_hh    = (const float*)d_in[23];
  const float* b_ih    = (const float*)d_in[24];
  const float* b_hh    = (const float*)d_in[25];

  char* p = (char*)d_ws;
  auto alloc = [&](size_t sz){ void* r = (void*)p; p += (sz + 255) & ~(size_t)255; return r; };
  float* xf    = (float*)alloc(8192ull*1024*4);
  u16*   h16   = (u16*)  alloc(8192ull*1024*2);
  u16*   big   = (u16*)  alloc(8192ull*4096*2);
  u16*   o16   = (u16*)  alloc(8192ull*1024*2);
  float* gates = (float*)alloc(512ull*4096*4);
  float* cst   = (float*)alloc(512ull*1024*4);
  u16*   hst   = (u16*)  alloc(512ull*1024*2);
  float* cs    = (float*)alloc(32ull*1024*4);
  float* smod  = (float*)alloc(32ull*6144*4);
  float* tmod  = (float*)alloc(32ull*6144*4);
  float* rmod  = (float*)alloc(32ull*3072*4);
  u16*   wT    = (u16*)  alloc(4096ull*1024*2);
  u16*   whhT  = (u16*)  alloc(4096ull*1024*2);
  float* bihh  = (float*)alloc(4096*4);

  dim3 tb(32,8);
  auto T = [&](const float* in, u16* out, int R, int C){
    transpose_f2b<<<dim3(C/32, R/32), tb, 0, stream>>>(in, out, R, C);
  };
  auto GEMM = [&](int kind, const u16* A, const u16* BT, void* out,
                  const float* b1, const u16* add, long astr, int M, int N, int K){
    dim3 g(N/128, M/128);
    switch(kind){
      case 0: gemm_nt<0><<<g,256,0,stream>>>(A,BT,(u16*)out,nullptr,nullptr,nullptr,0,M,N,K); break;
      case 1: gemm_nt<1><<<g,256,0,stream>>>(A,BT,(u16*)out,nullptr,b1,nullptr,0,M,N,K); break;
      case 2: gemm_nt<2><<<g,256,0,stream>>>(A,BT,(u16*)out,nullptr,b1,nullptr,0,M,N,K); break;
      case 3: gemm_nt<3><<<g,256,0,stream>>>(A,BT,nullptr,(float*)out,nullptr,add,astr,M,N,K); break;
    }
  };
  auto GEMM256 = [&](int kind, const u16* A, const u16* BT, u16* out,
                     const float* b1, int M, int N, int K){
    dim3 g(N/256, M/256);
    switch(kind){
      case 0: gemm256<0><<<g,512,0,stream>>>(A,BT,out,nullptr,M,N,K); break;
      case 1: gemm256<1><<<g,512,0,stream>>>(A,BT,out,b1,M,N,K); break;
      case 2: gemm256<2><<<g,512,0,stream>>>(A,BT,out,b1,M,N,K); break;
    }
  };
  auto MOD = [&](const float* W, const float* b, float* out, int Nw){
    mod_init<<<dim3(Nw/256,32),256,0,stream>>>(b, out, Nw);
    mod_part<<<dim3(Nw/256,4),256,0,stream>>>(cs, W, out, Nw);
  };

  silu_k<<<128,256,0,stream>>>(c, cs);
  MOD(s_ada_w, s_ada_b, smod, 6144);
  MOD(t_ada_w, t_ada_b, tmod, 6144);
  MOD(r_ada_w, r_ada_b, rmod, 3072);
  add_bias<<<16,256,0,stream>>>(b_ih, b_hh, bihh);

  // ---- spatial attention
  ln_first<<<8192,256,0,stream>>>(x, xf, smod, 6144, 0, 1024, h16);
  T(s_qkv_w, wT, 1024, 3072);
  GEMM256(0, h16, wT, big, nullptr, 8192, 3072, 1024);
  attn_spatial_mfma<<<dim3(16,32),256,0,stream>>>(big, h16);
  T(s_out_w, wT, 1024, 1024);
  GEMM(1, h16, wT, o16, s_out_b, nullptr, 0, 8192, 1024, 1024);
  gate_ln<<<8192,256,0,stream>>>(xf, o16, smod, 6144, 2048, 0, smod, 6144, 3072, 4096, h16, 0);
  // ---- spatial MLP
  T(s_mlp_w1, wT, 1024, 4096);
  GEMM256(2, h16, wT, big, s_mlp_b1, 8192, 4096, 1024);
  T(s_mlp_w2, wT, 4096, 1024);
  GEMM(1, big, wT, o16, s_mlp_b2, nullptr, 0, 8192, 1024, 4096);
  gate_ln<<<8192,256,0,stream>>>(xf, o16, smod, 6144, 5120, 0, tmod, 6144, 0, 1024, h16, 1);
  // ---- temporal attention
  T(t_qkv_w, wT, 1024, 3072);
  GEMM256(0, h16, wT, big, nullptr, 8192, 3072, 1024);
  attn_temporal<<<512,256,0,stream>>>(big, h16);
  T(t_out_w, wT, 1024, 1024);
  GEMM(1, h16, wT, o16, t_out_b, nullptr, 0, 8192, 1024, 1024);
  gate_ln<<<8192,256,0,stream>>>(xf, o16, tmod, 6144, 2048, 1, tmod, 6144, 3072, 4096, h16, 0);
  // ---- temporal MLP
  T(t_mlp_w1, wT, 1024, 4096);
  GEMM256(2, h16, wT, big, t_mlp_b1, 8192, 4096, 1024);
  T(t_mlp_w2, wT, 4096, 1024);
  GEMM(1, big, wT, o16, t_mlp_b2, nullptr, 0, 8192, 1024, 4096);
  gate_ln<<<8192,256,0,stream>>>(xf, o16, tmod, 6144, 5120, 0, rmod, 3072, 0, 1024, h16, 1);
  // ---- LSTM branch
  T(w_ih, wT, 1024, 4096);
  GEMM256(1, h16, wT, big, bihh, 8192, 4096, 1024);
  T(w_hh, whhT, 1024, 4096);
  hipMemsetAsync(cst, 0, 512ull*1024*4, stream);
  hipMemsetAsync(hst, 0, 512ull*1024*2, stream);
  for (int t=0; t<16; ++t){
    GEMM(3, hst, whhT, gates, nullptr, big + (size_t)t*4096, 16*4096, 512, 4096, 1024);
    lstm_point<<<512,256,0,stream>>>(gates, cst, hst, o16, t);
  }
  final_out<<<8192,256,0,stream>>>(xf, o16, rmod, (float*)d_out);
}

// Round 5
// 1910.649 us; speedup vs baseline: 1.1035x; 1.0353x over previous
//
#include <hip/hip_runtime.h>
#include <hip/hip_bf16.h>
#include <stdint.h>

typedef unsigned short u16;
typedef unsigned int u32;
typedef short short8 __attribute__((ext_vector_type(8)));
typedef float f32x4 __attribute__((ext_vector_type(4)));

// builtin barrier (no implicit waitcnt drain) + clobber-free counted waitcnt.
#define SBAR()   __builtin_amdgcn_s_barrier()
#define WAITV(n) asm volatile("s_waitcnt vmcnt(" #n ")")

__device__ __forceinline__ float bl(u32 x){ return __uint_as_float(x<<16); }
__device__ __forceinline__ float bh(u32 x){ return __uint_as_float(x & 0xffff0000u); }
__device__ __forceinline__ float b2f(u16 x){ return __uint_as_float(((u32)x)<<16); }
__device__ __forceinline__ u16 f2b(float f){
  u32 u = __float_as_uint(f);
  u32 r = (u + 0x7fffu + ((u>>16)&1u)) >> 16;
  return (u16)r;
}
__device__ __forceinline__ u32 pk2(float a, float b){ return (u32)f2b(a) | ((u32)f2b(b)<<16); }
__device__ __forceinline__ float tanh_f(float x){ return 1.f - 2.f/(__expf(2.f*x)+1.f); }
__device__ __forceinline__ float sigm(float x){ return 1.f/(1.f+__expf(-x)); }
__device__ __forceinline__ float gelu_t(float x){
  float u = 0.7978845608028654f*(x + 0.044715f*x*x*x);
  return 0.5f*x*(1.f + tanh_f(u));
}
// async global->LDS, 16B per lane; lds base must be wave-uniform
__device__ __forceinline__ void gld_lds16(const u16* g, u16* lds_base){
  __builtin_amdgcn_global_load_lds((const __attribute__((address_space(1))) void*)g,
                                   (__attribute__((address_space(3))) void*)lds_base,
                                   16, 0, 0);
}

// ---------------- transpose f32 [R,C] -> bf16 [C,R] ----------------
__global__ void transpose_f2b(const float* __restrict__ in, u16* __restrict__ out, int R, int C){
  __shared__ u16 t[32][33];
  int c0 = blockIdx.x*32, r0 = blockIdx.y*32;
  int tx = threadIdx.x, ty = threadIdx.y;   // 32 x 8
  #pragma unroll
  for (int i=0;i<4;++i) t[ty+i*8][tx] = f2b(in[(size_t)(r0+ty+i*8)*C + c0+tx]);
  __syncthreads();
  #pragma unroll
  for (int i=0;i<4;++i) out[(size_t)(c0+ty+i*8)*R + r0+tx] = t[tx][ty+i*8];
}

// ---------------- silu ----------------
__global__ void silu_k(const float* __restrict__ c, float* __restrict__ cs){
  int i = blockIdx.x*256 + threadIdx.x;
  float v = c[i];
  cs[i] = v * sigm(v);
}

// ---------------- b_ih + b_hh ----------------
__global__ void add_bias(const float* __restrict__ a, const float* __restrict__ b,
                         float* __restrict__ o){
  int i = blockIdx.x*256 + threadIdx.x;
  o[i] = a[i] + b[i];
}

// ---------------- mod GEMM: out[32,Nw] = cs@W + b (init + k-split atomic partials) ----------------
__global__ void mod_init(const float* __restrict__ b, float* __restrict__ out, int Nw){
  int j = blockIdx.x*256 + threadIdx.x;
  out[(size_t)blockIdx.y*Nw + j] = b[j];
}
__global__ __launch_bounds__(256)
void mod_part(const float* __restrict__ cs, const float* __restrict__ W,
              float* __restrict__ out, int Nw){
  int j  = blockIdx.x*256 + threadIdx.x;
  int k0 = blockIdx.y*256;
  __shared__ float csl[32*256];
  #pragma unroll
  for (int r=0;r<32;++r) csl[r*256 + threadIdx.x] = cs[(size_t)r*1024 + k0 + threadIdx.x];
  __syncthreads();
  float acc[32];
  #pragma unroll
  for (int r=0;r<32;++r) acc[r] = 0.f;
  for (int k=0;k<256;++k){
    float wv = W[(size_t)(k0+k)*Nw + j];
    #pragma unroll
    for (int r=0;r<32;++r) acc[r] += csl[r*256+k]*wv;
  }
  #pragma unroll
  for (int r=0;r<32;++r) atomicAdd(&out[(size_t)r*Nw + j], acc[r]);
}

// ---------------- LN(+mod) of input x, copy x -> xf ----------------
__global__ __launch_bounds__(256)
void ln_first(const float* __restrict__ xin, float* __restrict__ xf,
              const float* __restrict__ mod, int stride, int shift_off, int scale_off,
              u16* __restrict__ out){
  int tok = blockIdx.x, tid = threadIdx.x;
  float4 v = *(const float4*)(xin + (size_t)tok*1024 + tid*4);
  *(float4*)(xf + (size_t)tok*1024 + tid*4) = v;
  __shared__ float r1[256], r2[256];
  r1[tid] = v.x+v.y+v.z+v.w;
  r2[tid] = v.x*v.x+v.y*v.y+v.z*v.z+v.w*v.w;
  __syncthreads();
  for (int off=128; off>0; off>>=1){
    if (tid < off){ r1[tid] += r1[tid+off]; r2[tid] += r2[tid+off]; }
    __syncthreads();
  }
  float mean = r1[0]*(1.f/1024.f);
  float var  = r2[0]*(1.f/1024.f) - mean*mean;
  float rstd = rsqrtf(fmaxf(var,0.f) + 1e-6f);
  int bt = tok >> 8;
  const float* mr = mod + (size_t)bt*stride;
  int d = tid*4;
  float4 sh = *(const float4*)(mr + shift_off + d);
  float4 sc = *(const float4*)(mr + scale_off + d);
  float y0 = (v.x-mean)*rstd*(1.f+sc.x)+sh.x;
  float y1 = (v.y-mean)*rstd*(1.f+sc.y)+sh.y;
  float y2 = (v.z-mean)*rstd*(1.f+sc.z)+sh.z;
  float y3 = (v.w-mean)*rstd*(1.f+sc.w)+sh.w;
  uint2 ub; ub.x = pk2(y0,y1); ub.y = pk2(y2,y3);
  *(uint2*)(out + (size_t)tok*1024 + d) = ub;
}

// ---------------- fused: xf += gate*o ; then LN+mod of new xf -> h16 ----------------
__global__ __launch_bounds__(256)
void gate_ln(float* __restrict__ xf, const u16* __restrict__ o,
             const float* __restrict__ gmod, int gstride, int goff, int gperm,
             const float* __restrict__ lmod, int lstride, int shift_off, int scale_off,
             u16* __restrict__ out, int lperm){
  int tok = blockIdx.x, tid = threadIdx.x;
  int bt = tok >> 8;
  size_t stok = tok;
  if (gperm){ int b=tok>>12, t=(tok>>8)&15, ss=tok&255; stok = ((size_t)(b*256+ss)*16 + t); }
  int d = tid*4;
  uint2 u = *(const uint2*)(o + stok*1024 + d);
  float4 g = *(const float4*)(gmod + (size_t)bt*gstride + goff + d);
  float* xp = xf + (size_t)tok*1024 + d;
  float4 v = *(float4*)xp;
  v.x += bl(u.x)*g.x; v.y += bh(u.x)*g.y; v.z += bl(u.y)*g.z; v.w += bh(u.y)*g.w;
  *(float4*)xp = v;
  __shared__ float r1[256], r2[256];
  r1[tid] = v.x+v.y+v.z+v.w;
  r2[tid] = v.x*v.x+v.y*v.y+v.z*v.z+v.w*v.w;
  __syncthreads();
  for (int off=128; off>0; off>>=1){
    if (tid < off){ r1[tid] += r1[tid+off]; r2[tid] += r2[tid+off]; }
    __syncthreads();
  }
  float mean = r1[0]*(1.f/1024.f);
  float var  = r2[0]*(1.f/1024.f) - mean*mean;
  float rstd = rsqrtf(fmaxf(var,0.f) + 1e-6f);
  const float* mr = lmod + (size_t)bt*lstride;
  float4 sh = *(const float4*)(mr + shift_off + d);
  float4 sc = *(const float4*)(mr + scale_off + d);
  size_t otok = tok;
  if (lperm){ int b=tok>>12, t=(tok>>8)&15, ss=tok&255; otok = ((size_t)(b*256+ss)*16 + t); }
  float y0 = (v.x-mean)*rstd*(1.f+sc.x)+sh.x;
  float y1 = (v.y-mean)*rstd*(1.f+sc.y)+sh.y;
  float y2 = (v.z-mean)*rstd*(1.f+sc.z)+sh.z;
  float y3 = (v.w-mean)*rstd*(1.f+sc.w)+sh.w;
  uint2 ub; ub.x = pk2(y0,y1); ub.y = pk2(y2,y3);
  *(uint2*)(out + otok*1024 + d) = ub;
}

// ---------------- MFMA GEMM 128x128 (kept for N=1024 / M=512 shapes) ----------------
// KIND: 0 plain->bf16, 1 +bias(f32)->bf16, 2 +bias gelu->bf16, 3 +addend(bf16)->f32
template<int KIND>
__global__ __launch_bounds__(256, 2)
void gemm_nt(const u16* __restrict__ A, const u16* __restrict__ BT,
             u16* __restrict__ outb, float* __restrict__ outf,
             const float* __restrict__ biasf,
             const u16* __restrict__ addend, long astr,
             int M, int N, int K){
  __shared__ u16 As[128*32];
  __shared__ u16 Bs[128*32];
  const int tid  = threadIdx.x;
  const int wid  = tid >> 6, lane = tid & 63;
  const int l16  = lane & 15, quad = lane >> 4;
  const int wm   = wid >> 1,  wn   = wid & 1;
  const int m0   = blockIdx.y * 128, n0 = blockIdx.x * 128;
  f32x4 acc[4][4];
  #pragma unroll
  for (int i=0;i<4;++i)
    #pragma unroll
    for (int j=0;j<4;++j) acc[i][j] = (f32x4){0.f,0.f,0.f,0.f};

  for (int kt = 0; kt < K; kt += 32){
    __syncthreads();
    #pragma unroll
    for (int r = 0; r < 2; ++r){
      int flat = r*256 + wid*64 + lane;
      int row  = flat >> 2;          // 128 rows x 32 cols: 4 x 16B per row
      int sc   = ((flat & 3) ^ ((row >> 1) & 3)) << 3;   // pre-swizzled source chunk
      gld_lds16(&A [(size_t)(m0+row)*K + kt + sc], &As[(size_t)(r*256 + wid*64)*8]);
      gld_lds16(&BT[(size_t)(n0+row)*K + kt + sc], &Bs[(size_t)(r*256 + wid*64)*8]);
    }
    __syncthreads();
    short8 af[4], bfr[4];
    #pragma unroll
    for (int i=0;i<4;++i){
      int row = wm*64+i*16+l16;
      af[i]  = *(const short8*)&As[row*32 + ((quad ^ ((row>>1)&3))<<3)];
    }
    #pragma unroll
    for (int j=0;j<4;++j){
      int row = wn*64+j*16+l16;
      bfr[j] = *(const short8*)&Bs[row*32 + ((quad ^ ((row>>1)&3))<<3)];
    }
    #pragma unroll
    for (int i=0;i<4;++i)
      #pragma unroll
      for (int j=0;j<4;++j)
        acc[i][j] = __builtin_amdgcn_mfma_f32_16x16x32_bf16(af[i], bfr[j], acc[i][j], 0,0,0);
  }
  #pragma unroll
  for (int j=0;j<4;++j){
    int col = n0 + wn*64 + j*16 + l16;
    float bias = 0.f;
    if (KIND==1 || KIND==2) bias = biasf[col];
    #pragma unroll
    for (int i=0;i<4;++i){
      #pragma unroll
      for (int r=0;r<4;++r){
        int row = m0 + wm*64 + i*16 + quad*4 + r;
        float v = acc[i][j][r];
        if (KIND==1||KIND==2) v += bias;
        if (KIND==2) v = gelu_t(v);
        if (KIND==3){
          v += b2f(addend[(size_t)row*astr + col]);
          outf[(size_t)row*N + col] = v;
        } else {
          outb[(size_t)row*N + col] = f2b(v);
        }
      }
    }
  }
}

// ---------------- MFMA GEMM 256x256, 8 waves, counted-vmcnt ring, 1 barrier/K-tile --
// BK=32, 4-deep LDS ring (128 KiB), prefetch distance 3, ONE s_barrier per K-tile.
// No intra-tile barriers: waves decouple, so one wave's ds_reads overlap another's
// MFMAs (m114). Correctness: per-wave WAITV(8) before the tile-end barrier retires
// exactly tile t+1's 4 staged loads; all ds_reads of tile t were consumed by MFMAs
// (compiler lgkm waits) before that barrier, so staging into buf (t-1)&3 is safe.
// KIND: 0 plain->bf16, 1 +bias->bf16, 2 +bias gelu->bf16
template<int KIND>
__global__ __launch_bounds__(512, 2)
void gemm256(const u16* __restrict__ A, const u16* __restrict__ BT,
             u16* __restrict__ outb, const float* __restrict__ biasf,
             int M, int N, int K){
  __shared__ u16 S[4][2][256*32];     // [buf][op A/B][row*32+col]
  const int tid  = threadIdx.x;
  const int wid  = tid >> 6, lane = tid & 63;
  const int l16  = lane & 15, quad = lane >> 4;
  const int wm   = wid >> 2,  wn   = wid & 3;       // 2M x 4N wave grid
  const int m0   = blockIdx.y * 256, n0 = blockIdx.x * 256;
  const int NT   = K >> 5;

  f32x4 acc[8][4];
  #pragma unroll
  for (int i=0;i<8;++i)
    #pragma unroll
    for (int j=0;j<4;++j) acc[i][j] = (f32x4){0.f,0.f,0.f,0.f};

  // staging geometry: 1024 16B chunks per operand per K-tile; 2 loads/thread/operand
  const int f0  = tid,        r0s = f0 >> 2;
  const int f1  = 512 + tid,  r1s = f1 >> 2;
  const int c0s = ((f0 & 3) ^ ((r0s >> 1) & 3)) << 3;   // pre-swizzled source col
  const int c1s = ((f1 & 3) ^ ((r1s >> 1) & 3)) << 3;
  const int ld0 = (wid*64)*8;          // wave-uniform LDS elem offsets
  const int ld1 = (512 + wid*64)*8;

  auto stageA = [&](int t){
    int b = t & 3, kt = t << 5;
    gld_lds16(&A[(size_t)(m0 + r0s)*K + kt + c0s], &S[b][0][ld0]);
    gld_lds16(&A[(size_t)(m0 + r1s)*K + kt + c1s], &S[b][0][ld1]);
  };
  auto stageB = [&](int t){
    int b = t & 3, kt = t << 5;
    gld_lds16(&BT[(size_t)(n0 + r0s)*K + kt + c0s], &S[b][1][ld0]);
    gld_lds16(&BT[(size_t)(n0 + r1s)*K + kt + c1s], &S[b][1][ld1]);
  };

  // prologue: stage tiles 0..2
  const int npre = NT < 3 ? NT : 3;
  for (int t=0; t<npre; ++t){ stageA(t); stageB(t); }
  if (NT >= 3)      { WAITV(8); }
  else if (NT == 2) { WAITV(4); }
  else              { WAITV(0); }
  SBAR();

  for (int t=0; t<NT; ++t){
    const int b = t & 3;
    const u16* Ab = &S[b][0][0];
    const u16* Bb = &S[b][1][0];
    // issue next-tile staging first (HBM latency hides under this tile's work)
    if (t + 3 < NT){ stageA(t+3); stageB(t+3); }
    short8 bfr[4];
    #pragma unroll
    for (int j=0;j<4;++j){
      int row = wn*64 + j*16 + l16;
      bfr[j] = *(const short8*)&Bb[row*32 + ((quad ^ ((row>>1)&3))<<3)];
    }
    __builtin_amdgcn_s_setprio(1);
    #pragma unroll
    for (int i=0;i<8;++i){
      int row = wm*128 + i*16 + l16;
      short8 af = *(const short8*)&Ab[row*32 + ((quad ^ ((row>>1)&3))<<3)];
      #pragma unroll
      for (int j=0;j<4;++j)
        acc[i][j] = __builtin_amdgcn_mfma_f32_16x16x32_bf16(af, bfr[j], acc[i][j], 0,0,0);
    }
    __builtin_amdgcn_s_setprio(0);
    if (t + 3 < NT)      { WAITV(8); }   // tiles t+2,t+3 stay in flight
    else if (t + 2 < NT) { WAITV(4); }   // epilogue drain
    else if (t + 1 < NT) { WAITV(0); }
    SBAR();
  }

  // epilogue: i-outer so each output row's 128B line is completed by 4
  // consecutive 32B stores (write-combining friendly)
  float biasv[4];
  if (KIND==1 || KIND==2){
    #pragma unroll
    for (int j=0;j<4;++j) biasv[j] = biasf[n0 + wn*64 + j*16 + l16];
  }
  #pragma unroll
  for (int i=0;i<8;++i){
    #pragma unroll
    for (int r=0;r<4;++r){
      int row = m0 + wm*128 + i*16 + quad*4 + r;
      #pragma unroll
      for (int j=0;j<4;++j){
        int col = n0 + wn*64 + j*16 + l16;
        float v = acc[i][j][r];
        if (KIND==1||KIND==2) v += biasv[j];
        if (KIND==2) v = gelu_t(v);
        outb[(size_t)row*N + col] = f2b(v);
      }
    }
  }
}

// ---------------- spatial attention, MFMA flash (block = (h,n), wave = 64 q rows) ----------------
__global__ __launch_bounds__(256)
void attn_spatial_mfma(const u16* __restrict__ qkv, u16* __restrict__ out){
  constexpr int PAD = 80;
  __shared__ u16 Ks[64*PAD];
  __shared__ u16 Vt[64*PAD];
  __shared__ u16 Ps[4*64*PAD];
  int h = blockIdx.x, n = blockIdx.y;
  int tid = threadIdx.x, wid = tid>>6, lane = tid&63, l16 = lane&15, quad = lane>>4;
  u16* Pw = Ps + wid*64*PAD;
  int qrow_base = n*256 + wid*64;
  short8 qf[4][2];
  #pragma unroll
  for (int i=0;i<4;++i)
    #pragma unroll
    for (int c=0;c<2;++c)
      qf[i][c] = *(const short8*)(qkv + (size_t)(qrow_base + i*16 + l16)*3072 + h*64 + c*32 + quad*8);
  f32x4 Oc[4][4];
  float mrun[4][4], lrun[4][4];
  #pragma unroll
  for (int i=0;i<4;++i)
    #pragma unroll
    for (int j=0;j<4;++j){ Oc[i][j] = (f32x4){0.f,0.f,0.f,0.f}; mrun[i][j] = -30000.f; lrun[i][j] = 0.f; }

  for (int kt=0; kt<4; ++kt){
    __syncthreads();
    #pragma unroll
    for (int r=0;r<2;++r){
      int flat = tid + r*256;
      int row = flat>>3, c8 = (flat&7)<<3;   // 64 rows x 64 cols: 8 x 16B per row
      const u16* kp = qkv + (size_t)(n*256 + kt*64 + row)*3072 + 1024 + h*64 + c8;
      *(short8*)&Ks[row*PAD + c8] = *(const short8*)kp;
      short8 vv = *(const short8*)(kp + 1024);
      #pragma unroll
      for (int j=0;j<8;++j) Vt[(c8+j)*PAD + row] = ((const u16*)&vv)[j];
    }
    __syncthreads();
    f32x4 S[4][4];
    #pragma unroll
    for (int i=0;i<4;++i)
      #pragma unroll
      for (int jt=0;jt<4;++jt) S[i][jt] = (f32x4){0.f,0.f,0.f,0.f};
    #pragma unroll
    for (int c=0;c<2;++c){
      short8 kf[4];
      #pragma unroll
      for (int jt=0;jt<4;++jt) kf[jt] = *(const short8*)&Ks[(jt*16+l16)*PAD + c*32 + quad*8];
      #pragma unroll
      for (int i=0;i<4;++i)
        #pragma unroll
        for (int jt=0;jt<4;++jt)
          S[i][jt] = __builtin_amdgcn_mfma_f32_16x16x32_bf16(qf[i][c], kf[jt], S[i][jt], 0,0,0);
    }
    #pragma unroll
    for (int i=0;i<4;++i){
      #pragma unroll
      for (int r=0;r<4;++r){
        float rm = -30000.f;
        #pragma unroll
        for (int jt=0;jt<4;++jt){ S[i][jt][r] *= 0.125f; rm = fmaxf(rm, S[i][jt][r]); }
        #pragma unroll
        for (int off=1; off<16; off<<=1) rm = fmaxf(rm, __shfl_xor(rm, off));
        float mnew  = fmaxf(mrun[i][r], rm);
        float alpha = __expf(mrun[i][r] - mnew);
        mrun[i][r] = mnew;
        float ps = 0.f;
        #pragma unroll
        for (int jt=0;jt<4;++jt){ float pv = __expf(S[i][jt][r] - mnew); S[i][jt][r] = pv; ps += pv; }
        #pragma unroll
        for (int off=1; off<16; off<<=1) ps += __shfl_xor(ps, off);
        lrun[i][r] = lrun[i][r]*alpha + ps;
        #pragma unroll
        for (int dt=0;dt<4;++dt) Oc[i][dt][r] *= alpha;
        #pragma unroll
        for (int jt=0;jt<4;++jt) Pw[(i*16+quad*4+r)*PAD + jt*16 + l16] = f2b(S[i][jt][r]);
      }
    }
    #pragma unroll
    for (int c=0;c<2;++c){
      short8 pf[4], vf[4];
      #pragma unroll
      for (int i=0;i<4;++i)  pf[i]  = *(const short8*)&Pw[(i*16+l16)*PAD + c*32 + quad*8];
      #pragma unroll
      for (int dt=0;dt<4;++dt) vf[dt] = *(const short8*)&Vt[(dt*16+l16)*PAD + c*32 + quad*8];
      #pragma unroll
      for (int i=0;i<4;++i)
        #pragma unroll
        for (int dt=0;dt<4;++dt)
          Oc[i][dt] = __builtin_amdgcn_mfma_f32_16x16x32_bf16(pf[i], vf[dt], Oc[i][dt], 0,0,0);
    }
  }
  #pragma unroll
  for (int i=0;i<4;++i)
    #pragma unroll
    for (int r=0;r<4;++r){
      float rl = 1.f/lrun[i][r];
      int tok = qrow_base + i*16 + quad*4 + r;
      #pragma unroll
      for (int dt=0;dt<4;++dt)
        out[(size_t)tok*1024 + h*64 + dt*16 + l16] = f2b(Oc[i][dt][r]*rl);
    }
}

// ---------------- temporal causal attention (verified VALU version) ----------------
__global__ __launch_bounds__(256, 2)
void attn_temporal(const u16* __restrict__ qkv, u16* __restrict__ out){
  int n = blockIdx.x;
  int tid = threadIdx.x;
  int h = tid>>4, q = tid&15;
  __shared__ u16 KV[16*2048];
  #pragma unroll
  for (int i=0;i<16;++i){
    int u4i = tid + i*256;
    int e = u4i*8;
    int t = e>>11, cc = e&2047;
    *(uint4*)&KV[t*2048 + cc] = *(const uint4*)(qkv + ((size_t)(n*16+t)*3072 + 1024 + cc));
  }
  __syncthreads();
  float qr[64];
  const u16* qp = qkv + ((size_t)(n*16+q)*3072 + h*64);
  #pragma unroll
  for (int i=0;i<8;++i){
    uint4 u = *(const uint4*)(qp + i*8);
    qr[i*8+0]=bl(u.x)*0.125f; qr[i*8+1]=bh(u.x)*0.125f;
    qr[i*8+2]=bl(u.y)*0.125f; qr[i*8+3]=bh(u.y)*0.125f;
    qr[i*8+4]=bl(u.z)*0.125f; qr[i*8+5]=bh(u.z)*0.125f;
    qr[i*8+6]=bl(u.w)*0.125f; qr[i*8+7]=bh(u.w)*0.125f;
  }
  float sc[16]; float m = -30000.f;
  #pragma unroll
  for (int kv=0; kv<16; ++kv){
    const uint4* kr = (const uint4*)&KV[kv*2048 + h*64];
    float s = 0.f;
    #pragma unroll
    for (int i=0;i<8;++i){
      uint4 u = kr[i];
      s += qr[i*8+0]*bl(u.x) + qr[i*8+1]*bh(u.x) + qr[i*8+2]*bl(u.y) + qr[i*8+3]*bh(u.y)
         + qr[i*8+4]*bl(u.z) + qr[i*8+5]*bh(u.z) + qr[i*8+6]*bl(u.w) + qr[i*8+7]*bh(u.w);
    }
    s = (kv<=q) ? s : -30000.f;
    sc[kv]=s; m = fmaxf(m,s);
  }
  float l=0.f, acc[64];
  #pragma unroll
  for (int d=0;d<64;++d) acc[d]=0.f;
  #pragma unroll
  for (int kv=0; kv<16; ++kv){
    float p = __expf(sc[kv]-m);
    l += p;
    const uint4* vr = (const uint4*)&KV[kv*2048 + 1024 + h*64];
    #pragma unroll
    for (int i=0;i<8;++i){
      uint4 u = vr[i];
      acc[i*8+0]+=p*bl(u.x); acc[i*8+1]+=p*bh(u.x); acc[i*8+2]+=p*bl(u.y); acc[i*8+3]+=p*bh(u.y);
      acc[i*8+4]+=p*bl(u.z); acc[i*8+5]+=p*bh(u.z); acc[i*8+6]+=p*bl(u.w); acc[i*8+7]+=p*bh(u.w);
    }
  }
  float rl = 1.f/l;
  u16* op = out + ((size_t)(n*16+q)*1024 + h*64);
  #pragma unroll
  for (int i=0;i<8;++i){
    uint4 ub;
    ub.x = pk2(acc[i*8+0]*rl, acc[i*8+1]*rl);
    ub.y = pk2(acc[i*8+2]*rl, acc[i*8+3]*rl);
    ub.z = pk2(acc[i*8+4]*rl, acc[i*8+5]*rl);
    ub.w = pk2(acc[i*8+6]*rl, acc[i*8+7]*rl);
    *(uint4*)(op + i*8) = ub;
  }
}

// ---------------- LSTM pointwise ----------------
__global__ void lstm_point(const float* __restrict__ g4, float* __restrict__ cst,
                           u16* __restrict__ hst, u16* __restrict__ hout, int t){
  size_t i4 = ((size_t)blockIdx.x*256 + threadIdx.x)*4;
  int nn = (int)(i4 >> 10);
  int d  = (int)(i4 & 1023);
  const float* g = g4 + (size_t)nn*4096 + d;
  float4 gi = *(const float4*)(g);
  float4 gf = *(const float4*)(g+1024);
  float4 gg = *(const float4*)(g+2048);
  float4 go = *(const float4*)(g+3072);
  float4 c = *(float4*)(cst + i4);
  c.x = sigm(gf.x)*c.x + sigm(gi.x)*tanh_f(gg.x);
  c.y = sigm(gf.y)*c.y + sigm(gi.y)*tanh_f(gg.y);
  c.z = sigm(gf.z)*c.z + sigm(gi.z)*tanh_f(gg.z);
  c.w = sigm(gf.w)*c.w + sigm(gi.w)*tanh_f(gg.w);
  float h0 = sigm(go.x)*tanh_f(c.x);
  float h1 = sigm(go.y)*tanh_f(c.y);
  float h2 = sigm(go.z)*tanh_f(c.z);
  float h3 = sigm(go.w)*tanh_f(c.w);
  *(float4*)(cst + i4) = c;
  uint2 hb; hb.x = pk2(h0,h1); hb.y = pk2(h2,h3);
  *(uint2*)(hst + i4) = hb;
  *(uint2*)(hout + ((size_t)nn*16 + t)*1024 + d) = hb;
}

// ---------------- final: out(f32) = xf + gate(lstm_h) ----------------
__global__ void final_out(const float* __restrict__ xf, const u16* __restrict__ hout,
                          const float* __restrict__ rmod, float* __restrict__ out){
  size_t i4 = ((size_t)blockIdx.x*256 + threadIdx.x)*4;
  int tok = (int)(i4>>10), d = (int)(i4&1023);
  int bt = tok>>8;
  int b=tok>>12, t=(tok>>8)&15, ss=tok&255;
  size_t src = (((size_t)(b*256+ss)*16 + t)*1024) + d;
  uint2 u = *(const uint2*)(hout + src);
  float4 g = *(const float4*)(rmod + (size_t)bt*3072 + 2048 + d);
  float4 x = *(const float4*)(xf + i4);
  float4 o;
  o.x = x.x + bl(u.x)*g.x; o.y = x.y + bh(u.x)*g.y;
  o.z = x.z + bl(u.y)*g.z; o.w = x.w + bh(u.y)*g.w;
  *(float4*)(out + i4) = o;
}

extern "C" void kernel_launch(void* const* d_in, const int* in_sizes, int n_in,
                              void* d_out, int out_size, void* d_ws, size_t ws_size,
                              hipStream_t stream){
  (void)in_sizes; (void)n_in; (void)out_size; (void)ws_size;
  const float* x       = (const float*)d_in[0];
  const float* c       = (const float*)d_in[1];
  const float* s_ada_w = (const float*)d_in[2];
  const float* s_ada_b = (const float*)d_in[3];
  const float* t_ada_w = (const float*)d_in[4];
  const float* t_ada_b = (const float*)d_in[5];
  const float* r_ada_w = (const float*)d_in[6];
  const float* r_ada_b = (const float*)d_in[7];
  const float* s_qkv_w = (const float*)d_in[8];
  const float* s_out_w = (const float*)d_in[9];
  const float* s_out_b = (const float*)d_in[10];
  const float* t_qkv_w = (const float*)d_in[11];
  const float* t_out_w = (const float*)d_in[12];
  const float* t_out_b = (const float*)d_in[13];
  const float* s_mlp_w1= (const float*)d_in[14];
  const float* s_mlp_b1= (const float*)d_in[15];
  const float* s_mlp_w2= (const float*)d_in[16];
  const float* s_mlp_b2= (const float*)d_in[17];
  const float* t_mlp_w1= (const float*)d_in[18];
  const float* t_mlp_b1= (const float*)d_in[19];
  const float* t_mlp_w2= (const float*)d_in[20];
  const float* t_mlp_b2= (const float*)d_in[21];
  const float* w_ih    = (const float*)d_in[22];
  const float* w_hh    = (const float*)d_in[23];
  const float* b_ih    = (const float*)d_in[24];
  const float* b_hh    = (const float*)d_in[25];

  char* p = (char*)d_ws;
  auto alloc = [&](size_t sz){ void* r = (void*)p; p += (sz + 255) & ~(size_t)255; return r; };
  float* xf    = (float*)alloc(8192ull*1024*4);
  u16*   h16   = (u16*)  alloc(8192ull*1024*2);
  u16*   big   = (u16*)  alloc(8192ull*4096*2);
  u16*   o16   = (u16*)  alloc(8192ull*1024*2);
  float* gates = (float*)alloc(512ull*4096*4);
  float* cst   = (float*)alloc(512ull*1024*4);
  u16*   hst   = (u16*)  alloc(512ull*1024*2);
  float* cs    = (float*)alloc(32ull*1024*4);
  float* smod  = (float*)alloc(32ull*6144*4);
  float* tmod  = (float*)alloc(32ull*6144*4);
  float* rmod  = (float*)alloc(32ull*3072*4);
  u16*   wT    = (u16*)  alloc(4096ull*1024*2);
  u16*   whhT  = (u16*)  alloc(4096ull*1024*2);
  float* bihh  = (float*)alloc(4096*4);

  dim3 tb(32,8);
  auto T = [&](const float* in, u16* out, int R, int C){
    transpose_f2b<<<dim3(C/32, R/32), tb, 0, stream>>>(in, out, R, C);
  };
  auto GEMM = [&](int kind, const u16* A, const u16* BT, void* out,
                  const float* b1, const u16* add, long astr, int M, int N, int K){
    dim3 g(N/128, M/128);
    switch(kind){
      case 0: gemm_nt<0><<<g,256,0,stream>>>(A,BT,(u16*)out,nullptr,nullptr,nullptr,0,M,N,K); break;
      case 1: gemm_nt<1><<<g,256,0,stream>>>(A,BT,(u16*)out,nullptr,b1,nullptr,0,M,N,K); break;
      case 2: gemm_nt<2><<<g,256,0,stream>>>(A,BT,(u16*)out,nullptr,b1,nullptr,0,M,N,K); break;
      case 3: gemm_nt<3><<<g,256,0,stream>>>(A,BT,nullptr,(float*)out,nullptr,add,astr,M,N,K); break;
    }
  };
  auto GEMM256 = [&](int kind, const u16* A, const u16* BT, u16* out,
                     const float* b1, int M, int N, int K){
    dim3 g(N/256, M/256);
    switch(kind){
      case 0: gemm256<0><<<g,512,0,stream>>>(A,BT,out,nullptr,M,N,K); break;
      case 1: gemm256<1><<<g,512,0,stream>>>(A,BT,out,b1,M,N,K); break;
      case 2: gemm256<2><<<g,512,0,stream>>>(A,BT,out,b1,M,N,K); break;
    }
  };
  auto MOD = [&](const float* W, const float* b, float* out, int Nw){
    mod_init<<<dim3(Nw/256,32),256,0,stream>>>(b, out, Nw);
    mod_part<<<dim3(Nw/256,4),256,0,stream>>>(cs, W, out, Nw);
  };

  silu_k<<<128,256,0,stream>>>(c, cs);
  MOD(s_ada_w, s_ada_b, smod, 6144);
  MOD(t_ada_w, t_ada_b, tmod, 6144);
  MOD(r_ada_w, r_ada_b, rmod, 3072);
  add_bias<<<16,256,0,stream>>>(b_ih, b_hh, bihh);

  // ---- spatial attention
  ln_first<<<8192,256,0,stream>>>(x, xf, smod, 6144, 0, 1024, h16);
  T(s_qkv_w, wT, 1024, 3072);
  GEMM256(0, h16, wT, big, nullptr, 8192, 3072, 1024);
  attn_spatial_mfma<<<dim3(16,32),256,0,stream>>>(big, h16);
  T(s_out_w, wT, 1024, 1024);
  GEMM(1, h16, wT, o16, s_out_b, nullptr, 0, 8192, 1024, 1024);
  gate_ln<<<8192,256,0,stream>>>(xf, o16, smod, 6144, 2048, 0, smod, 6144, 3072, 4096, h16, 0);
  // ---- spatial MLP
  T(s_mlp_w1, wT, 1024, 4096);
  GEMM256(2, h16, wT, big, s_mlp_b1, 8192, 4096, 1024);
  T(s_mlp_w2, wT, 4096, 1024);
  GEMM(1, big, wT, o16, s_mlp_b2, nullptr, 0, 8192, 1024, 4096);
  gate_ln<<<8192,256,0,stream>>>(xf, o16, smod, 6144, 5120, 0, tmod, 6144, 0, 1024, h16, 1);
  // ---- temporal attention
  T(t_qkv_w, wT, 1024, 3072);
  GEMM256(0, h16, wT, big, nullptr, 8192, 3072, 1024);
  attn_temporal<<<512,256,0,stream>>>(big, h16);
  T(t_out_w, wT, 1024, 1024);
  GEMM(1, h16, wT, o16, t_out_b, nullptr, 0, 8192, 1024, 1024);
  gate_ln<<<8192,256,0,stream>>>(xf, o16, tmod, 6144, 2048, 1, tmod, 6144, 3072, 4096, h16, 0);
  // ---- temporal MLP
  T(t_mlp_w1, wT, 1024, 4096);
  GEMM256(2, h16, wT, big, t_mlp_b1, 8192, 4096, 1024);
  T(t_mlp_w2, wT, 4096, 1024);
  GEMM(1, big, wT, o16, t_mlp_b2, nullptr, 0, 8192, 1024, 4096);
  gate_ln<<<8192,256,0,stream>>>(xf, o16, tmod, 6144, 5120, 0, rmod, 3072, 0, 1024, h16, 1);
  // ---- LSTM branch
  T(w_ih, wT, 1024, 4096);
  GEMM256(1, h16, wT, big, bihh, 8192, 4096, 1024);
  T(w_hh, whhT, 1024, 4096);
  hipMemsetAsync(cst, 0, 512ull*1024*4, stream);
  hipMemsetAsync(hst, 0, 512ull*1024*2, stream);
  for (int t=0; t<16; ++t){
    GEMM(3, hst, whhT, gates, nullptr, big + (size_t)t*4096, 16*4096, 512, 4096, 1024);
    lstm_point<<<512,256,0,stream>>>(gates, cst, hst, o16, t);
  }
  final_out<<<8192,256,0,stream>>>(xf, o16, rmod, (float*)d_out);
}